// Round 1
// baseline (2973.816 us; speedup 1.0000x reference)
//
#include <hip/hip_runtime.h>
#include <math.h>

#define BB 32
#define SS 50
#define NBS 1600      // B*S
#define LL 20
#define EE 300
#define NH 16
#define VD 16
#define HID 256
#define QD 200
#define XPAD 304      // padded row stride for LDS x/q tiles (float4-aligned)

// ---------------------------------------------------------------------------
// Kernel 1: per (bs, head) fused MHA:  gather x -> q = x*Wq+bq -> scores ->
// softmax -> ctx -> v = ctx*Wv+bv -> write into news_embedding (d_out chunk 1)
// grid: NBS*NH blocks, 320 threads (5 waves)
// ---------------------------------------------------------------------------
__global__ __launch_bounds__(320) void nrms_attn_kernel(
    const int*   __restrict__ news,   // [NBS*LL]
    const float* __restrict__ emb,    // [50000*EE]
    const float* __restrict__ qW,     // [NH*EE*EE]
    const float* __restrict__ qB,     // [NH*EE]
    const float* __restrict__ vW,     // [NH*EE*VD]
    const float* __restrict__ vB,     // [NH*VD]
    float*       __restrict__ out1)   // [NBS*LL*HID]  (news_embedding)
{
    const int blk = blockIdx.x;
    const int bs  = blk >> 4;
    const int n   = blk & 15;
    const int tid = threadIdx.x;

    __shared__ float xs[LL][XPAD];  // x tile [20][300]
    __shared__ float qs[LL][XPAD];  // q tile, later reused for ctx
    __shared__ float sc[LL][LL];    // scores -> attn

    // ---- gather x: 20 rows of 300 floats (row-contiguous, coalesced) ----
    for (int idx = tid; idx < LL * 75; idx += 320) {
        const int l  = idx / 75;
        const int e4 = (idx % 75) * 4;
        const int row = news[bs * LL + l];
        const float4 v = *reinterpret_cast<const float4*>(emb + (size_t)row * EE + e4);
        *reinterpret_cast<float4*>(&xs[l][e4]) = v;
    }
    __syncthreads();

    const int lg = tid / 75;          // 0..3 (valid when tid<300)
    const int fg = tid % 75;
    const int l0 = lg * 5;
    const int f0 = fg * 4;

    // ---- q = x * Wq[n] + bq[n]   (5 l  x 4 f per thread) ----
    if (tid < 300) {
        float acc[5][4];
        const float4 bq = *reinterpret_cast<const float4*>(qB + n * EE + f0);
        #pragma unroll
        for (int li = 0; li < 5; ++li) {
            acc[li][0] = bq.x; acc[li][1] = bq.y; acc[li][2] = bq.z; acc[li][3] = bq.w;
        }
        const float* wp = qW + (size_t)n * EE * EE + f0;
        for (int e0 = 0; e0 < EE; e0 += 4) {
            const float4 w0 = *reinterpret_cast<const float4*>(wp + (e0 + 0) * EE);
            const float4 w1 = *reinterpret_cast<const float4*>(wp + (e0 + 1) * EE);
            const float4 w2 = *reinterpret_cast<const float4*>(wp + (e0 + 2) * EE);
            const float4 w3 = *reinterpret_cast<const float4*>(wp + (e0 + 3) * EE);
            #pragma unroll
            for (int li = 0; li < 5; ++li) {
                const float4 xv = *reinterpret_cast<const float4*>(&xs[l0 + li][e0]);
                acc[li][0] = fmaf(xv.x, w0.x, fmaf(xv.y, w1.x, fmaf(xv.z, w2.x, fmaf(xv.w, w3.x, acc[li][0]))));
                acc[li][1] = fmaf(xv.x, w0.y, fmaf(xv.y, w1.y, fmaf(xv.z, w2.y, fmaf(xv.w, w3.y, acc[li][1]))));
                acc[li][2] = fmaf(xv.x, w0.z, fmaf(xv.y, w1.z, fmaf(xv.z, w2.z, fmaf(xv.w, w3.z, acc[li][2]))));
                acc[li][3] = fmaf(xv.x, w0.w, fmaf(xv.y, w1.w, fmaf(xv.z, w2.w, fmaf(xv.w, w3.w, acc[li][3]))));
            }
        }
        #pragma unroll
        for (int li = 0; li < 5; ++li) {
            qs[l0 + li][f0 + 0] = acc[li][0];
            qs[l0 + li][f0 + 1] = acc[li][1];
            qs[l0 + li][f0 + 2] = acc[li][2];
            qs[l0 + li][f0 + 3] = acc[li][3];
        }
    }
    __syncthreads();

    // ---- scores = q * x^T / sqrt(E) ----
    const float rsE = 0.057735026918962584f;  // 1/sqrt(300)
    for (int idx = tid; idx < LL * LL; idx += 320) {
        const int l = idx / LL;
        const int m = idx % LL;
        float s = 0.f;
        for (int e0 = 0; e0 < EE; e0 += 4) {
            const float4 a = *reinterpret_cast<const float4*>(&qs[l][e0]);
            const float4 b = *reinterpret_cast<const float4*>(&xs[m][e0]);
            s += a.x * b.x + a.y * b.y + a.z * b.z + a.w * b.w;
        }
        sc[l][m] = s * rsE;
    }
    __syncthreads();

    // ---- softmax over m (one thread per row l) ----
    if (tid < LL) {
        float mx = -1e30f;
        #pragma unroll
        for (int m = 0; m < LL; ++m) mx = fmaxf(mx, sc[tid][m]);
        float sum = 0.f;
        #pragma unroll
        for (int m = 0; m < LL; ++m) { const float e = __expf(sc[tid][m] - mx); sc[tid][m] = e; sum += e; }
        const float inv = 1.f / sum;
        #pragma unroll
        for (int m = 0; m < LL; ++m) sc[tid][m] *= inv;
    }
    __syncthreads();

    // ---- ctx = attn * x   (same 5l x 4e register tile), overwrite qs ----
    if (tid < 300) {
        float cacc[5][4];
        #pragma unroll
        for (int li = 0; li < 5; ++li)
            cacc[li][0] = cacc[li][1] = cacc[li][2] = cacc[li][3] = 0.f;
        #pragma unroll 4
        for (int m = 0; m < LL; ++m) {
            const float4 xv = *reinterpret_cast<const float4*>(&xs[m][f0]);
            #pragma unroll
            for (int li = 0; li < 5; ++li) {
                const float a = sc[l0 + li][m];
                cacc[li][0] = fmaf(a, xv.x, cacc[li][0]);
                cacc[li][1] = fmaf(a, xv.y, cacc[li][1]);
                cacc[li][2] = fmaf(a, xv.z, cacc[li][2]);
                cacc[li][3] = fmaf(a, xv.w, cacc[li][3]);
            }
        }
        #pragma unroll
        for (int li = 0; li < 5; ++li) {
            qs[l0 + li][f0 + 0] = cacc[li][0];
            qs[l0 + li][f0 + 1] = cacc[li][1];
            qs[l0 + li][f0 + 2] = cacc[li][2];
            qs[l0 + li][f0 + 3] = cacc[li][3];
        }
    }
    __syncthreads();

    // ---- v = ctx * Wv[n] + bv[n]; write into mha layout [l][n*16+vi] ----
    {
        const int l  = tid >> 4;   // 0..19 (tid<320)
        const int vi = tid & 15;
        float acc = vB[n * VD + vi];
        const float* wv = vW + n * EE * VD + vi;
        for (int e0 = 0; e0 < EE; e0 += 4) {
            const float4 c4 = *reinterpret_cast<const float4*>(&qs[l][e0]);
            acc = fmaf(c4.x, wv[(e0 + 0) * VD],
                  fmaf(c4.y, wv[(e0 + 1) * VD],
                  fmaf(c4.z, wv[(e0 + 2) * VD],
                  fmaf(c4.w, wv[(e0 + 3) * VD], acc))));
        }
        out1[((size_t)bs * LL + l) * HID + n * VD + vi] = acc;
    }
}

// ---------------------------------------------------------------------------
// Kernel 2: additive attention pooling per bs
// grid: NBS blocks, 256 threads
// ---------------------------------------------------------------------------
__global__ __launch_bounds__(256) void nrms_pool_kernel(
    const float* __restrict__ out1,   // mha [NBS*LL*HID]
    const float* __restrict__ keyW,   // [QD][HID]
    const float* __restrict__ keyB,   // [QD]
    const float* __restrict__ query,  // [QD]
    float*       __restrict__ out2)   // [NBS*HID] (news_repr)
{
    const int bs  = blockIdx.x;
    const int tid = threadIdx.x;

    __shared__ float mh[LL][HID];     // 20 KB
    __shared__ float akq[LL][QD];     // 16 KB: query[d]*tanh(add_key)
    __shared__ float s2v[LL];

    // load mha tile (flat float4)
    for (int idx = tid; idx < LL * HID / 4; idx += 256) {
        reinterpret_cast<float4*>(&mh[0][0])[idx] =
            reinterpret_cast<const float4*>(out1 + (size_t)bs * LL * HID)[idx];
    }
    __syncthreads();

    // akq[l][d] = query[d] * tanh(mh[l]·keyW[d] + keyB[d])
    for (int idx = tid; idx < LL * QD; idx += 256) {
        const int l = idx / QD;
        const int d = idx % QD;
        float a = keyB[d];
        const float* kw = keyW + d * HID;
        for (int h = 0; h < HID; h += 4) {
            const float4 m4 = *reinterpret_cast<const float4*>(&mh[l][h]);
            const float4 k4 = *reinterpret_cast<const float4*>(kw + h);
            a = fmaf(m4.x, k4.x, fmaf(m4.y, k4.y, fmaf(m4.z, k4.z, fmaf(m4.w, k4.w, a))));
        }
        akq[l][d] = query[d] * tanhf(a);
    }
    __syncthreads();

    // s2[l] = sum_d akq[l][d] / sqrt(QD)
    if (tid < LL) {
        float s = 0.f;
        for (int d = 0; d < QD; ++d) s += akq[tid][d];
        s2v[tid] = s * 0.07071067811865475f;  // 1/sqrt(200)
    }
    __syncthreads();

    // softmax over l (serial, tiny)
    if (tid == 0) {
        float mx = -1e30f;
        #pragma unroll
        for (int l = 0; l < LL; ++l) mx = fmaxf(mx, s2v[l]);
        float sum = 0.f;
        #pragma unroll
        for (int l = 0; l < LL; ++l) { const float e = __expf(s2v[l] - mx); s2v[l] = e; sum += e; }
        const float inv = 1.f / sum;
        #pragma unroll
        for (int l = 0; l < LL; ++l) s2v[l] *= inv;
    }
    __syncthreads();

    // news_repr[h] = sum_l a2[l] * mh[l][h]
    {
        const int h = tid;  // 256 threads == HID
        float acc = 0.f;
        #pragma unroll
        for (int l = 0; l < LL; ++l) acc = fmaf(s2v[l], mh[l][h], acc);
        out2[(size_t)bs * HID + h] = acc;
    }
}

extern "C" void kernel_launch(void* const* d_in, const int* in_sizes, int n_in,
                              void* d_out, int out_size, void* d_ws, size_t ws_size,
                              hipStream_t stream) {
    const int*   news  = (const int*)d_in[0];
    const float* emb   = (const float*)d_in[1];
    const float* qW    = (const float*)d_in[2];
    const float* qB    = (const float*)d_in[3];
    const float* vW    = (const float*)d_in[4];
    const float* vB    = (const float*)d_in[5];
    const float* keyW  = (const float*)d_in[6];
    const float* keyB  = (const float*)d_in[7];
    const float* query = (const float*)d_in[8];

    float* out1 = (float*)d_out;            // news_embedding: 32*50*20*1*256 = 8192000
    float* out2 = out1 + 8192000;           // news_repr:      32*50*256      = 409600

    hipLaunchKernelGGL(nrms_attn_kernel, dim3(NBS * NH), dim3(320), 0, stream,
                       news, emb, qW, qB, vW, vB, out1);
    hipLaunchKernelGGL(nrms_pool_kernel, dim3(NBS), dim3(256), 0, stream,
                       out1, keyW, keyB, query, out2);
}

// Round 2
// 2347.483 us; speedup vs baseline: 1.2668x; 1.2668x over previous
//
#include <hip/hip_runtime.h>
#include <math.h>

#define NBS 1600      // B*S
#define LL 20
#define EE 300
#define NH 16
#define VD 16
#define HID 256
#define QD 200

// padded LDS strides (shorts) to break 32-bank conflicts on ds_read_b128
#define XP 328        // 32x328: row stride 656B == 164 dwords == 4 mod 32 banks
#define TP 40         // 320x40: row stride 80B == 20 dwords mod 32
#define AP 40

typedef short bf16x8 __attribute__((ext_vector_type(8)));
typedef float f32x4 __attribute__((ext_vector_type(4)));

__device__ __forceinline__ short f2b(float f) {
    union { float f; unsigned u; } c; c.f = f;
    unsigned r = (c.u + 0x7FFFu + ((c.u >> 16) & 1u)) >> 16;  // RNE
    return (short)r;
}

__device__ __forceinline__ float ftanh(float a) {
    a = fminf(fmaxf(a, -15.f), 15.f);
    float t = __expf(2.f * a);
    return (t - 1.f) / (t + 1.f);
}

// ---------------------------------------------------------------------------
// Wq [n][e][f] fp32  ->  WqT bf16 [n][f(304 pad)][e(320 pad)]
// grid (10,10,16), block (32,32); LDS-tiled transpose, coalesced both sides
// ---------------------------------------------------------------------------
__global__ __launch_bounds__(1024) void transpose_qw(
    const float* __restrict__ qW, short* __restrict__ wqt)
{
    __shared__ float t[32][33];
    const int n = blockIdx.z;
    const int e0 = blockIdx.x * 32, f0 = blockIdx.y * 32;
    const int tx = threadIdx.x, ty = threadIdx.y;
    const int e = e0 + ty, f = f0 + tx;
    t[ty][tx] = (e < EE && f < EE) ? qW[(size_t)n * EE * EE + e * EE + f] : 0.f;
    __syncthreads();
    const int fo = f0 + ty, eo = e0 + tx;
    if (fo < 304)
        wqt[(size_t)n * 304 * 320 + fo * 320 + eo] = f2b(t[tx][ty]);
}

// Wv [n][e][v] fp32 -> WvT bf16 [n][v][e(320 pad)]
__global__ void conv_vw(const float* __restrict__ vW, short* __restrict__ wvt) {
    int idx = blockIdx.x * 256 + threadIdx.x;
    if (idx >= NH * VD * 320) return;
    int e = idx % 320;
    int v = (idx / 320) % VD;
    int n = idx / (320 * VD);
    wvt[idx] = (e < EE) ? f2b(vW[(size_t)n * EE * VD + e * VD + v]) : (short)0;
}

// ---------------------------------------------------------------------------
// Fused MHA per bs, MFMA bf16. grid 1600, block 256 (4 waves).
// ---------------------------------------------------------------------------
__global__ __launch_bounds__(256) void nrms_attn_mfma(
    const int*   __restrict__ news,
    const float* __restrict__ emb,
    const short* __restrict__ wqt,   // [NH][304][320] bf16
    const float* __restrict__ qB,    // [NH][300]
    const short* __restrict__ wvt,   // [NH][16][320] bf16
    const float* __restrict__ vB,    // [NH][16]
    float*       __restrict__ out1)  // [NBS][20][256]
{
    const int bs   = blockIdx.x;
    const int tid  = threadIdx.x;
    const int wave = tid >> 6;
    const int lane = tid & 63;
    const int lr   = lane & 15;   // A-row / B-row(N) / D-col
    const int lg   = lane >> 4;   // k-group

    __shared__ short xs[32][XP];   // x  [l][e]  bf16 (pads zero)
    __shared__ short xT[320][TP];  // x^T [e][l] bf16
    __shared__ short qs[32][XP];   // q, then ctx  [l][e/f]
    __shared__ float sc[32][33];   // scores fp32
    __shared__ short at[32][AP];   // attn bf16 [l][m]

    // zero x/xT/q tiles (pads must be 0; avoids 0*inf NaNs too)
    {
        int* z = (int*)&xs[0][0];
        for (int i = tid; i < 32 * XP / 2; i += 256) z[i] = 0;
        z = (int*)&qs[0][0];
        for (int i = tid; i < 32 * XP / 2; i += 256) z[i] = 0;
        z = (int*)&xT[0][0];
        for (int i = tid; i < 320 * TP / 2; i += 256) z[i] = 0;
    }
    __syncthreads();

    // gather x rows -> xs (bf16) and xT
    for (int idx = tid; idx < LL * 75; idx += 256) {
        const int l = idx / 75, e4 = (idx % 75) * 4;
        const int row = news[bs * LL + l];
        const float4 v = *reinterpret_cast<const float4*>(emb + (size_t)row * EE + e4);
        const short b0 = f2b(v.x), b1 = f2b(v.y), b2 = f2b(v.z), b3 = f2b(v.w);
        xs[l][e4] = b0; xs[l][e4 + 1] = b1; xs[l][e4 + 2] = b2; xs[l][e4 + 3] = b3;
        xT[e4][l] = b0; xT[e4 + 1][l] = b1; xT[e4 + 2][l] = b2; xT[e4 + 3][l] = b3;
    }
    __syncthreads();

    for (int n = 0; n < NH; ++n) {
        const short* wq = wqt + (size_t)n * 304 * 320;

        // ---- q = x * Wq[n] + bq : M=32, N=304 (19 tiles), K=320 (10 steps) ----
        for (int t = wave; t < 38; t += 4) {
            const int mt = t & 1, nt = t >> 1;
            f32x4 acc = {0.f, 0.f, 0.f, 0.f};
            const short* ap = &xs[mt * 16 + lr][lg * 8];
            const short* bp = wq + (nt * 16 + lr) * 320 + lg * 8;
            #pragma unroll
            for (int k = 0; k < 10; ++k) {
                bf16x8 a = *reinterpret_cast<const bf16x8*>(ap + k * 32);
                bf16x8 b = *reinterpret_cast<const bf16x8*>(bp + k * 32);
                acc = __builtin_amdgcn_mfma_f32_16x16x32_bf16(a, b, acc, 0, 0, 0);
            }
            const int col = nt * 16 + lr;
            const float bias = (col < EE) ? qB[n * EE + col] : 0.f;
            #pragma unroll
            for (int r = 0; r < 4; ++r)
                qs[mt * 16 + lg * 4 + r][col] = f2b(acc[r] + bias);
        }
        __syncthreads();

        // ---- scores = q * x^T / sqrt(E) : 4 tiles, one per wave ----
        {
            const int mt = wave & 1, nt = wave >> 1;
            f32x4 acc = {0.f, 0.f, 0.f, 0.f};
            const short* ap = &qs[mt * 16 + lr][lg * 8];
            const short* bp = &xs[nt * 16 + lr][lg * 8];
            #pragma unroll
            for (int k = 0; k < 10; ++k) {
                bf16x8 a = *reinterpret_cast<const bf16x8*>(ap + k * 32);
                bf16x8 b = *reinterpret_cast<const bf16x8*>(bp + k * 32);
                acc = __builtin_amdgcn_mfma_f32_16x16x32_bf16(a, b, acc, 0, 0, 0);
            }
            #pragma unroll
            for (int r = 0; r < 4; ++r)
                sc[mt * 16 + lg * 4 + r][nt * 16 + lr] = acc[r] * 0.057735026918962584f;
        }
        __syncthreads();

        // ---- softmax rows 0..19 (cols 0..19); fill attn bf16 (pads zero) ----
        if (tid < LL) {
            float mx = -1e30f;
            #pragma unroll
            for (int m = 0; m < LL; ++m) mx = fmaxf(mx, sc[tid][m]);
            float ev[LL], sum = 0.f;
            #pragma unroll
            for (int m = 0; m < LL; ++m) { ev[m] = __expf(sc[tid][m] - mx); sum += ev[m]; }
            const float inv = 1.f / sum;
            #pragma unroll
            for (int m = 0; m < LL; ++m) at[tid][m] = f2b(ev[m] * inv);
            #pragma unroll
            for (int m = LL; m < 32; ++m) at[tid][m] = 0;
        } else if (tid < 32) {
            #pragma unroll
            for (int m = 0; m < 32; ++m) at[tid][m] = 0;
        }
        __syncthreads();

        // ---- ctx = attn * x : M=32, N=304 (19 tiles), K=32 (1 step) -> qs ----
        for (int t = wave; t < 38; t += 4) {
            const int mt = t & 1, nt = t >> 1;
            bf16x8 a = *reinterpret_cast<const bf16x8*>(&at[mt * 16 + lr][lg * 8]);
            bf16x8 b = *reinterpret_cast<const bf16x8*>(&xT[nt * 16 + lr][lg * 8]);
            f32x4 acc = {0.f, 0.f, 0.f, 0.f};
            acc = __builtin_amdgcn_mfma_f32_16x16x32_bf16(a, b, acc, 0, 0, 0);
            const int col = nt * 16 + lr;
            #pragma unroll
            for (int r = 0; r < 4; ++r)
                qs[mt * 16 + lg * 4 + r][col] = f2b(acc[r]);
        }
        __syncthreads();

        // ---- v = ctx * Wv[n] + bv : M=32 (2 tiles), N=16, K=320 ----
        if (wave < 2) {
            const int mt = wave;
            f32x4 acc = {0.f, 0.f, 0.f, 0.f};
            const short* ap = &qs[mt * 16 + lr][lg * 8];
            const short* bp = wvt + (size_t)n * VD * 320 + lr * 320 + lg * 8;
            #pragma unroll
            for (int k = 0; k < 10; ++k) {
                bf16x8 a = *reinterpret_cast<const bf16x8*>(ap + k * 32);
                bf16x8 b = *reinterpret_cast<const bf16x8*>(bp + k * 32);
                acc = __builtin_amdgcn_mfma_f32_16x16x32_bf16(a, b, acc, 0, 0, 0);
            }
            #pragma unroll
            for (int r = 0; r < 4; ++r) {
                const int row = mt * 16 + lg * 4 + r;
                if (row < LL)
                    out1[((size_t)bs * LL + row) * HID + n * VD + lr] = acc[r] + vB[n * VD + lr];
            }
        }
        __syncthreads();  // protect qs before next head's q-GEMM
    }
}

// ---------------------------------------------------------------------------
// Additive attention pooling per bs. grid 1600, block 256.
// ---------------------------------------------------------------------------
__global__ __launch_bounds__(256) void nrms_pool_kernel(
    const float* __restrict__ out1,
    const float* __restrict__ keyW,   // [QD][HID]
    const float* __restrict__ keyB,   // [QD]
    const float* __restrict__ query,  // [QD]
    float*       __restrict__ out2)   // [NBS][HID]
{
    const int bs  = blockIdx.x;
    const int tid = threadIdx.x;
    const int wave = tid >> 6;
    const int lane = tid & 63;

    __shared__ float mh[LL][HID];
    __shared__ float akq[LL][QD];
    __shared__ float s2v[LL];

    for (int idx = tid; idx < LL * HID / 4; idx += 256) {
        reinterpret_cast<float4*>(&mh[0][0])[idx] =
            reinterpret_cast<const float4*>(out1 + (size_t)bs * LL * HID)[idx];
    }
    __syncthreads();

    for (int idx = tid; idx < LL * QD; idx += 256) {
        const int l = idx / QD;
        const int d = idx % QD;
        float a = keyB[d];
        const float* kw = keyW + d * HID;
        for (int h = 0; h < HID; h += 4) {
            const float4 m4 = *reinterpret_cast<const float4*>(&mh[l][h]);
            const float4 k4 = *reinterpret_cast<const float4*>(kw + h);
            a = fmaf(m4.x, k4.x, fmaf(m4.y, k4.y, fmaf(m4.z, k4.z, fmaf(m4.w, k4.w, a))));
        }
        akq[l][d] = query[d] * ftanh(a);
    }
    __syncthreads();

    // s2[l]: wave-parallel reduction
    for (int l = wave; l < LL; l += 4) {
        float s = 0.f;
        for (int d = lane; d < QD; d += 64) s += akq[l][d];
        #pragma unroll
        for (int off = 32; off; off >>= 1) s += __shfl_down(s, off);
        if (lane == 0) s2v[l] = s * 0.07071067811865475f;
    }
    __syncthreads();

    if (tid == 0) {
        float mx = -1e30f;
        #pragma unroll
        for (int l = 0; l < LL; ++l) mx = fmaxf(mx, s2v[l]);
        float sum = 0.f;
        #pragma unroll
        for (int l = 0; l < LL; ++l) { const float e = __expf(s2v[l] - mx); s2v[l] = e; sum += e; }
        const float inv = 1.f / sum;
        #pragma unroll
        for (int l = 0; l < LL; ++l) s2v[l] *= inv;
    }
    __syncthreads();

    {
        const int h = tid;
        float acc = 0.f;
        #pragma unroll
        for (int l = 0; l < LL; ++l) acc = fmaf(s2v[l], mh[l][h], acc);
        out2[(size_t)bs * HID + h] = acc;
    }
}

extern "C" void kernel_launch(void* const* d_in, const int* in_sizes, int n_in,
                              void* d_out, int out_size, void* d_ws, size_t ws_size,
                              hipStream_t stream) {
    const int*   news  = (const int*)d_in[0];
    const float* emb   = (const float*)d_in[1];
    const float* qW    = (const float*)d_in[2];
    const float* qB    = (const float*)d_in[3];
    const float* vW    = (const float*)d_in[4];
    const float* vB    = (const float*)d_in[5];
    const float* keyW  = (const float*)d_in[6];
    const float* keyB  = (const float*)d_in[7];
    const float* query = (const float*)d_in[8];

    float* out1 = (float*)d_out;            // news_embedding: 8192000 floats
    float* out2 = out1 + 8192000;           // news_repr: 409600 floats

    short* wqt = (short*)d_ws;                      // 16*304*320 bf16
    short* wvt = wqt + (size_t)NH * 304 * 320;      // 16*16*320 bf16

    hipLaunchKernelGGL(transpose_qw, dim3(10, 10, 16), dim3(32, 32), 0, stream, qW, wqt);
    hipLaunchKernelGGL(conv_vw, dim3(320), dim3(256), 0, stream, vW, wvt);
    hipLaunchKernelGGL(nrms_attn_mfma, dim3(NBS), dim3(256), 0, stream,
                       news, emb, wqt, qB, wvt, vB, out1);
    hipLaunchKernelGGL(nrms_pool_kernel, dim3(NBS), dim3(256), 0, stream,
                       out1, keyW, keyB, query, out2);
}

// Round 3
// 1591.995 us; speedup vs baseline: 1.8680x; 1.4746x over previous
//
#include <hip/hip_runtime.h>
#include <math.h>

#define NBS 1600      // B*S
#define LL 20
#define EE 300
#define NH 16
#define VD 16
#define HID 256
#define QD 200

// LDS row strides in SHORTS — chosen ODD in dwords to spread banks
#define XP 330        // 165 dwords, odd
#define TP 42         // 21 dwords, odd
#define AP 34         // 17 dwords, odd

typedef short bf16x8 __attribute__((ext_vector_type(8)));
typedef float f32x4 __attribute__((ext_vector_type(4)));

__device__ __forceinline__ short f2b(float f) {
    union { float f; unsigned u; } c; c.f = f;
    unsigned r = (c.u + 0x7FFFu + ((c.u >> 16) & 1u)) >> 16;  // RNE
    return (short)r;
}

__device__ __forceinline__ float ftanh(float a) {
    a = fminf(fmaxf(a, -15.f), 15.f);
    float t = __expf(2.f * a);
    return (t - 1.f) / (t + 1.f);
}

// ---------------------------------------------------------------------------
// Wq [n][e][f] fp32  ->  WqT bf16 [n][f(304)][e(320)]   (k-contiguous rows)
// ---------------------------------------------------------------------------
__global__ __launch_bounds__(1024) void transpose_qw(
    const float* __restrict__ qW, short* __restrict__ wqt)
{
    __shared__ float t[32][33];
    const int n = blockIdx.z;
    const int e0 = blockIdx.x * 32, f0 = blockIdx.y * 32;
    const int tx = threadIdx.x, ty = threadIdx.y;
    const int e = e0 + ty, f = f0 + tx;
    t[ty][tx] = (e < EE && f < EE) ? qW[(size_t)n * EE * EE + e * EE + f] : 0.f;
    __syncthreads();
    const int fo = f0 + ty, eo = e0 + tx;
    if (fo < 304)
        wqt[(size_t)n * 304 * 320 + fo * 320 + eo] = f2b(t[tx][ty]);
}

// Wv [n][e][v] fp32 -> WvT bf16 [n][v][e(320)]
__global__ void conv_vw(const float* __restrict__ vW, short* __restrict__ wvt) {
    int idx = blockIdx.x * 256 + threadIdx.x;
    if (idx >= NH * VD * 320) return;
    int e = idx % 320;
    int v = (idx / 320) % VD;
    int n = idx / (320 * VD);
    wvt[idx] = (e < EE) ? f2b(vW[(size_t)n * EE * VD + e * VD + v]) : (short)0;
}

// keyW [200][256] fp32 -> bf16 [208][256] (rows >=200 zero)
__global__ void conv_kw(const float* __restrict__ keyW, short* __restrict__ kwb) {
    int idx = blockIdx.x * 256 + threadIdx.x;
    if (idx >= 208 * 256) return;
    int d = idx >> 8;
    kwb[idx] = (d < QD) ? f2b(keyW[idx]) : (short)0;
}

// ---------------------------------------------------------------------------
// Fused MHA per bs, MFMA bf16. grid 1600, block 512 (8 waves).
// ---------------------------------------------------------------------------
__global__ __launch_bounds__(512) void nrms_attn_mfma(
    const int*   __restrict__ news,
    const float* __restrict__ emb,
    const short* __restrict__ wqt,   // [NH][304][320] bf16
    const float* __restrict__ qB,    // [NH][300]
    const short* __restrict__ wvt,   // [NH][16][320] bf16
    const float* __restrict__ vB,    // [NH][16]
    float*       __restrict__ out1)  // [NBS][20][256]
{
    const int bs   = blockIdx.x;
    const int tid  = threadIdx.x;
    const int wave = tid >> 6;
    const int lane = tid & 63;
    const int lr   = lane & 15;   // A/B row index; D col
    const int lg   = lane >> 4;   // k-group; D row group

    __shared__ short xs[32][XP];   // x  [l][e]
    __shared__ short xT[320][TP];  // x^T [e][l]
    __shared__ short qs[32][XP];   // q, then ctx
    __shared__ float sc[32][33];   // scores fp32
    __shared__ short at[32][AP];   // attn bf16

    // one-time zero (pads must be 0)
    {
        int* z = (int*)&xs[0][0];
        for (int i = tid; i < 32 * XP / 2; i += 512) z[i] = 0;
        z = (int*)&qs[0][0];
        for (int i = tid; i < 32 * XP / 2; i += 512) z[i] = 0;
        z = (int*)&xT[0][0];
        for (int i = tid; i < 320 * TP / 2; i += 512) z[i] = 0;
    }
    __syncthreads();

    // gather x rows -> xs (bf16) and xT
    for (int idx = tid; idx < LL * 75; idx += 512) {
        const int l = idx / 75, e4 = (idx % 75) * 4;
        const int row = news[bs * LL + l];
        const float4 v = *reinterpret_cast<const float4*>(emb + (size_t)row * EE + e4);
        const short b0 = f2b(v.x), b1 = f2b(v.y), b2 = f2b(v.z), b3 = f2b(v.w);
        xs[l][e4] = b0; xs[l][e4 + 1] = b1; xs[l][e4 + 2] = b2; xs[l][e4 + 3] = b3;
        xT[e4][l] = b0; xT[e4 + 1][l] = b1; xT[e4 + 2][l] = b2; xT[e4 + 3][l] = b3;
    }
    __syncthreads();

    for (int n = 0; n < NH; ++n) {
        const short* wq = wqt + (size_t)n * 304 * 320;

        // ---- q = x*Wq+bq : 19 col-tile pairs, B shared by both m-tiles ----
        for (int p = wave; p < 19; p += 8) {
            f32x4 acc0 = {0.f, 0.f, 0.f, 0.f};
            f32x4 acc1 = {0.f, 0.f, 0.f, 0.f};
            const short* a0p = &xs[lr][lg * 8];
            const short* a1p = &xs[16 + lr][lg * 8];
            const short* bp  = wq + (p * 16 + lr) * 320 + lg * 8;
            #pragma unroll
            for (int k = 0; k < 10; ++k) {
                bf16x8 b  = *reinterpret_cast<const bf16x8*>(bp + k * 32);
                bf16x8 a0 = *reinterpret_cast<const bf16x8*>(a0p + k * 32);
                bf16x8 a1 = *reinterpret_cast<const bf16x8*>(a1p + k * 32);
                acc0 = __builtin_amdgcn_mfma_f32_16x16x32_bf16(a0, b, acc0, 0, 0, 0);
                acc1 = __builtin_amdgcn_mfma_f32_16x16x32_bf16(a1, b, acc1, 0, 0, 0);
            }
            const int col = p * 16 + lr;
            const float bias = (col < EE) ? qB[n * EE + col] : 0.f;
            #pragma unroll
            for (int r = 0; r < 4; ++r) {
                qs[lg * 4 + r][col]      = f2b(acc0[r] + bias);
                qs[16 + lg * 4 + r][col] = f2b(acc1[r] + bias);
            }
        }
        __syncthreads();

        // ---- scores = q*x^T/sqrt(E) : 4 tiles on waves 0-3 ----
        if (wave < 4) {
            const int mt = wave & 1, nt = wave >> 1;
            f32x4 acc = {0.f, 0.f, 0.f, 0.f};
            const short* ap = &qs[mt * 16 + lr][lg * 8];
            const short* bp = &xs[nt * 16 + lr][lg * 8];
            #pragma unroll
            for (int k = 0; k < 10; ++k) {
                bf16x8 a = *reinterpret_cast<const bf16x8*>(ap + k * 32);
                bf16x8 b = *reinterpret_cast<const bf16x8*>(bp + k * 32);
                acc = __builtin_amdgcn_mfma_f32_16x16x32_bf16(a, b, acc, 0, 0, 0);
            }
            #pragma unroll
            for (int r = 0; r < 4; ++r)
                sc[mt * 16 + lg * 4 + r][nt * 16 + lr] = acc[r] * 0.057735026918962584f;
        }
        __syncthreads();

        // ---- softmax rows 0..19 ----
        if (tid < LL) {
            float mx = -1e30f;
            #pragma unroll
            for (int m = 0; m < LL; ++m) mx = fmaxf(mx, sc[tid][m]);
            float ev[LL], sum = 0.f;
            #pragma unroll
            for (int m = 0; m < LL; ++m) { ev[m] = __expf(sc[tid][m] - mx); sum += ev[m]; }
            const float inv = 1.f / sum;
            #pragma unroll
            for (int m = 0; m < LL; ++m) at[tid][m] = f2b(ev[m] * inv);
            #pragma unroll
            for (int m = LL; m < 32; ++m) at[tid][m] = 0;
        } else if (tid < 32) {
            int* zr = (int*)&at[tid][0];
            #pragma unroll
            for (int m = 0; m < 16; ++m) zr[m] = 0;
        }
        __syncthreads();

        // ---- ctx = attn*x : 19 col-tile pairs, single K-step ----
        for (int p = wave; p < 19; p += 8) {
            bf16x8 b  = *reinterpret_cast<const bf16x8*>(&xT[p * 16 + lr][lg * 8]);
            bf16x8 a0 = *reinterpret_cast<const bf16x8*>(&at[lr][lg * 8]);
            bf16x8 a1 = *reinterpret_cast<const bf16x8*>(&at[16 + lr][lg * 8]);
            f32x4 z = {0.f, 0.f, 0.f, 0.f};
            f32x4 c0 = __builtin_amdgcn_mfma_f32_16x16x32_bf16(a0, b, z, 0, 0, 0);
            f32x4 c1 = __builtin_amdgcn_mfma_f32_16x16x32_bf16(a1, b, z, 0, 0, 0);
            const int col = p * 16 + lr;
            #pragma unroll
            for (int r = 0; r < 4; ++r) {
                qs[lg * 4 + r][col]      = f2b(c0[r]);
                qs[16 + lg * 4 + r][col] = f2b(c1[r]);
            }
        }
        __syncthreads();

        // ---- v = ctx*Wv+bv : 2 m-tiles on waves 0-1 ----
        if (wave < 2) {
            const int mt = wave;
            f32x4 acc = {0.f, 0.f, 0.f, 0.f};
            const short* ap = &qs[mt * 16 + lr][lg * 8];
            const short* bp = wvt + (size_t)n * VD * 320 + lr * 320 + lg * 8;
            #pragma unroll
            for (int k = 0; k < 10; ++k) {
                bf16x8 a = *reinterpret_cast<const bf16x8*>(ap + k * 32);
                bf16x8 b = *reinterpret_cast<const bf16x8*>(bp + k * 32);
                acc = __builtin_amdgcn_mfma_f32_16x16x32_bf16(a, b, acc, 0, 0, 0);
            }
            #pragma unroll
            for (int r = 0; r < 4; ++r) {
                const int row = mt * 16 + lg * 4 + r;
                if (row < LL)
                    out1[((size_t)bs * LL + row) * HID + n * VD + lr] = acc[r] + vB[n * VD + lr];
            }
        }
        __syncthreads();  // qs reused next head
    }
}

// ---------------------------------------------------------------------------
// Additive attention pooling per bs, MFMA for add_key. grid 1600, block 256.
// ---------------------------------------------------------------------------
__global__ __launch_bounds__(256) void nrms_pool_mfma(
    const float* __restrict__ out1,
    const short* __restrict__ kwb,    // [208][256] bf16
    const float* __restrict__ keyB,   // [200]
    const float* __restrict__ query,  // [200]
    float*       __restrict__ out2)   // [NBS][256]
{
    const int bs   = blockIdx.x;
    const int tid  = threadIdx.x;
    const int wave = tid >> 6;
    const int lane = tid & 63;
    const int lr   = lane & 15;
    const int lg   = lane >> 4;

    __shared__ float mh[LL][257];    // fp32 copy for final weighted sum
    __shared__ short mhb[32][266];   // bf16 for MFMA A (133 dwords/row, odd)
    __shared__ float s2p[32];

    // zero mhb rows 20..31 (only k-cols 0..255 matter)
    for (int i = tid; i < 12 * 128; i += 256) {
        const int r = 20 + i / 128, c = (i % 128) * 2;
        *reinterpret_cast<int*>(&mhb[r][c]) = 0;
    }
    if (tid < 32) s2p[tid] = 0.f;

    // load mh tile + bf16 convert
    for (int idx = tid; idx < LL * 64; idx += 256) {
        const int l = idx >> 6, h4 = (idx & 63) * 4;
        const float4 v = *reinterpret_cast<const float4*>(out1 + ((size_t)bs * LL + l) * HID + h4);
        mh[l][h4] = v.x; mh[l][h4 + 1] = v.y; mh[l][h4 + 2] = v.z; mh[l][h4 + 3] = v.w;
        mhb[l][h4] = f2b(v.x); mhb[l][h4 + 1] = f2b(v.y);
        mhb[l][h4 + 2] = f2b(v.z); mhb[l][h4 + 3] = f2b(v.w);
    }
    __syncthreads();

    // add_key GEMM: M=32 (2 mt), N=208 (13 nt), K=256 (8 steps)
    for (int t = wave; t < 26; t += 4) {
        const int mt = t & 1, nt = t >> 1;
        f32x4 acc = {0.f, 0.f, 0.f, 0.f};
        const short* ap = &mhb[mt * 16 + lr][lg * 8];
        const short* bp = kwb + (nt * 16 + lr) * 256 + lg * 8;
        #pragma unroll
        for (int k = 0; k < 8; ++k) {
            bf16x8 a = *reinterpret_cast<const bf16x8*>(ap + k * 32);
            bf16x8 b = *reinterpret_cast<const bf16x8*>(bp + k * 32);
            acc = __builtin_amdgcn_mfma_f32_16x16x32_bf16(a, b, acc, 0, 0, 0);
        }
        const int d = nt * 16 + lr;
        const float qd = (d < QD) ? query[d] : 0.f;
        const float kb = (d < QD) ? keyB[d] : 0.f;
        float vals[4];
        #pragma unroll
        for (int r = 0; r < 4; ++r) vals[r] = qd * ftanh(acc[r] + kb);
        // reduce over the 16 lr-lanes (lane bits 0..3)
        #pragma unroll
        for (int off = 1; off < 16; off <<= 1) {
            #pragma unroll
            for (int r = 0; r < 4; ++r) vals[r] += __shfl_xor(vals[r], off);
        }
        if (lr == 0) {
            #pragma unroll
            for (int r = 0; r < 4; ++r)
                atomicAdd(&s2p[mt * 16 + lg * 4 + r], vals[r]);
        }
    }
    __syncthreads();

    // softmax over l (tiny, serial)
    if (tid == 0) {
        float mx = -1e30f;
        #pragma unroll
        for (int l = 0; l < LL; ++l) mx = fmaxf(mx, s2p[l] * 0.07071067811865475f);
        float sum = 0.f;
        float e[LL];
        #pragma unroll
        for (int l = 0; l < LL; ++l) { e[l] = __expf(s2p[l] * 0.07071067811865475f - mx); sum += e[l]; }
        const float inv = 1.f / sum;
        #pragma unroll
        for (int l = 0; l < LL; ++l) s2p[l] = e[l] * inv;
    }
    __syncthreads();

    // news_repr[h] = sum_l a2[l] * mh[l][h]
    {
        const int h = tid;
        float acc = 0.f;
        #pragma unroll
        for (int l = 0; l < LL; ++l) acc = fmaf(s2p[l], mh[l][h], acc);
        out2[(size_t)bs * HID + h] = acc;
    }
}

extern "C" void kernel_launch(void* const* d_in, const int* in_sizes, int n_in,
                              void* d_out, int out_size, void* d_ws, size_t ws_size,
                              hipStream_t stream) {
    const int*   news  = (const int*)d_in[0];
    const float* emb   = (const float*)d_in[1];
    const float* qW    = (const float*)d_in[2];
    const float* qB    = (const float*)d_in[3];
    const float* vW    = (const float*)d_in[4];
    const float* vB    = (const float*)d_in[5];
    const float* keyW  = (const float*)d_in[6];
    const float* keyB  = (const float*)d_in[7];
    const float* query = (const float*)d_in[8];

    float* out1 = (float*)d_out;            // news_embedding: 8192000 floats
    float* out2 = out1 + 8192000;           // news_repr: 409600 floats

    short* wqt = (short*)d_ws;                      // 16*304*320
    short* wvt = wqt + (size_t)NH * 304 * 320;      // 16*16*320
    short* kwb = wvt + (size_t)NH * VD * 320;       // 208*256

    hipLaunchKernelGGL(transpose_qw, dim3(10, 10, 16), dim3(32, 32), 0, stream, qW, wqt);
    hipLaunchKernelGGL(conv_vw, dim3(320), dim3(256), 0, stream, vW, wvt);
    hipLaunchKernelGGL(conv_kw, dim3(208), dim3(256), 0, stream, keyW, kwb);
    hipLaunchKernelGGL(nrms_attn_mfma, dim3(NBS), dim3(512), 0, stream,
                       news, emb, wqt, qB, wvt, vB, out1);
    hipLaunchKernelGGL(nrms_pool_mfma, dim3(NBS), dim3(256), 0, stream,
                       out1, kwb, keyB, query, out2);
}

// Round 4
// 431.618 us; speedup vs baseline: 6.8899x; 3.6884x over previous
//
#include <hip/hip_runtime.h>
#include <math.h>

#define NBS 1600      // B*S
#define LL 20
#define EE 300
#define NH 16
#define VD 16
#define HID 256
#define QD 200

typedef short bf16x8 __attribute__((ext_vector_type(8)));
typedef float f32x4 __attribute__((ext_vector_type(4)));

__device__ __forceinline__ short f2b(float f) {
    union { float f; unsigned u; } c; c.f = f;
    unsigned r = (c.u + 0x7FFFu + ((c.u >> 16) & 1u)) >> 16;  // RNE
    return (short)r;
}

__device__ __forceinline__ float ftanh(float a) {
    a = fminf(fmaxf(a, -15.f), 15.f);
    float t = __expf(2.f * a);
    return (t - 1.f) / (t + 1.f);
}

// ===========================================================================
// NEW PATH (needs ~40.4 MB ws)
// ===========================================================================

// news/emb -> Xb bf16 [32000][320]; col300 = 1.0 (bias channel), 301..319 = 0
__global__ void build_xb(const int* __restrict__ news, const float* __restrict__ emb,
                         short* __restrict__ Xb) {
    int idx = blockIdx.x * 256 + threadIdx.x;     // one per 4 elems
    if (idx >= 32000 * 80) return;
    int i = idx / 80, e4 = (idx % 80) * 4;
    short4 o;
    if (e4 < 300) {
        const float4 v = *reinterpret_cast<const float4*>(emb + (size_t)news[i] * EE + e4);
        o.x = f2b(v.x); o.y = f2b(v.y); o.z = f2b(v.z); o.w = f2b(v.w);
    } else if (e4 == 300) {
        o.x = (short)0x3F80; o.y = 0; o.z = 0; o.w = 0;
    } else {
        o.x = o.y = o.z = o.w = 0;
    }
    *reinterpret_cast<short4*>(Xb + (size_t)i * 320 + e4) = o;
}

// Wq [n][e][f] -> WqT bf16 [n][f(320)][e(320)], col300 = qB, zero rows f>=300
__global__ __launch_bounds__(1024) void build_wqt(
    const float* __restrict__ qW, const float* __restrict__ qB, short* __restrict__ WqT)
{
    __shared__ float t[32][33];
    const int n = blockIdx.z;
    const int e0 = blockIdx.x * 32, f0 = blockIdx.y * 32;
    const int tx = threadIdx.x, ty = threadIdx.y;
    const int e = e0 + ty, f = f0 + tx;
    t[ty][tx] = (e < EE && f < EE) ? qW[((size_t)n * EE + e) * EE + f] : 0.f;
    __syncthreads();
    const int fo = f0 + ty, eo = e0 + tx;
    float val;
    if (fo >= EE)      val = 0.f;
    else if (eo < EE)  val = t[tx][ty];
    else if (eo == EE) val = qB[n * EE + fo];
    else               val = 0.f;
    WqT[((size_t)n * 320 + fo) * 320 + eo] = f2b(val);
}

// Wv [n][e][v] -> WvT bf16 [256][320] rows c=n*16+vd, col300 = vB
__global__ void build_wvt(const float* __restrict__ vW, const float* __restrict__ vB,
                          short* __restrict__ WvT) {
    int idx = blockIdx.x * 256 + threadIdx.x;
    if (idx >= 256 * 320) return;
    int c = idx / 320, e = idx % 320;
    int n = c >> 4, vd = c & 15;
    float val = (e < EE) ? vW[((size_t)n * EE + e) * VD + vd]
                         : (e == EE ? vB[n * VD + vd] : 0.f);
    WvT[idx] = f2b(val);
}

// keyW [200][256] fp32 -> bf16 [208][256] (rows >=200 zero)
__global__ void conv_kw(const float* __restrict__ keyW, short* __restrict__ kwb) {
    int idx = blockIdx.x * 256 + threadIdx.x;
    if (idx >= 208 * 256) return;
    int d = idx >> 8;
    kwb[idx] = (d < QD) ? f2b(keyW[idx]) : (short)0;
}

// xv = Xb * WvT^T : [32000][256] bf16.  128x128 tile, 4 waves.
__global__ __launch_bounds__(256) void gemm_xv(
    const short* __restrict__ Xb, const short* __restrict__ WvT, short* __restrict__ xv)
{
    const int nt0 = blockIdx.x * 128;
    const size_t mt0 = (size_t)blockIdx.y * 128;
    const int tid = threadIdx.x, wave = tid >> 6, lane = tid & 63;
    const int lr = lane & 15, lg = lane >> 4;
    const int wm = wave & 1, wn = wave >> 1;

    __shared__ short As[128][66];
    __shared__ short Bs[128][66];
    f32x4 acc[4][4] = {};

    for (int ks = 0; ks < 5; ++ks) {
        __syncthreads();
        for (int u = 0; u < 4; ++u) {
            int idx = u * 256 + tid;          // 0..1023
            int rr = idx >> 3, c8 = idx & 7;
            *reinterpret_cast<bf16x8*>(&As[rr][c8 * 8]) =
                *reinterpret_cast<const bf16x8*>(Xb + (mt0 + rr) * 320 + ks * 64 + c8 * 8);
            *reinterpret_cast<bf16x8*>(&Bs[rr][c8 * 8]) =
                *reinterpret_cast<const bf16x8*>(WvT + (size_t)(nt0 + rr) * 320 + ks * 64 + c8 * 8);
        }
        __syncthreads();
        #pragma unroll
        for (int kk = 0; kk < 2; ++kk) {
            bf16x8 af[4], bfv[4];
            #pragma unroll
            for (int f = 0; f < 4; ++f)
                af[f] = *reinterpret_cast<const bf16x8*>(&As[wm * 64 + f * 16 + lr][kk * 32 + lg * 8]);
            #pragma unroll
            for (int f = 0; f < 4; ++f)
                bfv[f] = *reinterpret_cast<const bf16x8*>(&Bs[wn * 64 + f * 16 + lr][kk * 32 + lg * 8]);
            #pragma unroll
            for (int i = 0; i < 4; ++i)
                #pragma unroll
                for (int j = 0; j < 4; ++j)
                    acc[i][j] = __builtin_amdgcn_mfma_f32_16x16x32_bf16(af[i], bfv[j], acc[i][j], 0, 0, 0);
        }
    }
    #pragma unroll
    for (int i = 0; i < 4; ++i)
        #pragma unroll
        for (int j = 0; j < 4; ++j)
            #pragma unroll
            for (int r = 0; r < 4; ++r)
                xv[(mt0 + wm * 64 + i * 16 + lg * 4 + r) * 256 + nt0 + wn * 64 + j * 16 + lr]
                    = f2b(acc[i][j][r]);
}

// ---------------------------------------------------------------------------
// qattn: one block per (group of 4 bs, head). 512 threads (8 waves).
// q = x*WqT (M=80,N=320,K=320) -> scores -> in-register softmax -> v=attn*xv
// ---------------------------------------------------------------------------
__global__ __launch_bounds__(512) void qattn(
    const short* __restrict__ Xb,    // [32000][320]
    const short* __restrict__ WqT,   // [16][320][320]
    const short* __restrict__ xv,    // [32000][256]
    float*       __restrict__ out1)  // [32000][256]
{
    const int g = blockIdx.x;        // group of 4 bs
    const int n = blockIdx.y;        // head
    const int tid = threadIdx.x, wave = tid >> 6, lane = tid & 63;
    const int lr = lane & 15, lg = lane >> 4;
    const size_t row0 = (size_t)g * 80;

    __shared__ short xs[80][330];    // x tile (odd-dword stride)
    __shared__ short qs[80][330];    // q tile
    __shared__ short Bb[320][32];    // WqT k-chunk [f][32k]
    __shared__ short atw[4][32][34]; // per-bs attn scratch

    // zero atw (rows 20..31 / cols 20..31 must stay zero)
    for (int i = tid; i < 4 * 32 * 34 / 2; i += 512)
        reinterpret_cast<int*>(atw)[i] = 0;

    // load xs: 80 rows x 320 cols
    for (int idx = tid; idx < 3200; idx += 512) {
        int l = idx / 40, c8 = idx % 40;
        bf16x8 v = *reinterpret_cast<const bf16x8*>(Xb + (row0 + l) * 320 + c8 * 8);
        *reinterpret_cast<bf16x8*>(&xs[l][c8 * 8]) = v;
    }

    const short* wh = WqT + (size_t)n * 320 * 320;
    // prologue: load B chunk ks=0 to regs
    bf16x8 br0, br1, br2;
    {
        int i0 = tid, i1 = 512 + tid, i2 = 1024 + tid;
        br0 = *reinterpret_cast<const bf16x8*>(wh + (size_t)(i0 >> 2) * 320 + (i0 & 3) * 8);
        br1 = *reinterpret_cast<const bf16x8*>(wh + (size_t)(i1 >> 2) * 320 + (i1 & 3) * 8);
        if (tid < 256)
            br2 = *reinterpret_cast<const bf16x8*>(wh + (size_t)(i2 >> 2) * 320 + (i2 & 3) * 8);
    }

    f32x4 acc[5][3] = {};
    for (int ks = 0; ks < 10; ++ks) {
        __syncthreads();   // all reads of Bb (prev iter) + xs writes done
        // write chunk ks
        *reinterpret_cast<bf16x8*>(&Bb[0][0] + (size_t)tid * 8) = br0;
        *reinterpret_cast<bf16x8*>(&Bb[0][0] + (size_t)(512 + tid) * 8) = br1;
        if (tid < 256)
            *reinterpret_cast<bf16x8*>(&Bb[0][0] + (size_t)(1024 + tid) * 8) = br2;
        __syncthreads();   // Bb ready
        if (ks < 9) {      // issue next chunk loads; fly during compute
            int k1 = ks + 1;
            int i0 = tid, i1 = 512 + tid, i2 = 1024 + tid;
            br0 = *reinterpret_cast<const bf16x8*>(wh + (size_t)(i0 >> 2) * 320 + k1 * 32 + (i0 & 3) * 8);
            br1 = *reinterpret_cast<const bf16x8*>(wh + (size_t)(i1 >> 2) * 320 + k1 * 32 + (i1 & 3) * 8);
            if (tid < 256)
                br2 = *reinterpret_cast<const bf16x8*>(wh + (size_t)(i2 >> 2) * 320 + k1 * 32 + (i2 & 3) * 8);
        }
        // compute chunk ks
        bf16x8 af[5];
        #pragma unroll
        for (int mt = 0; mt < 5; ++mt)
            af[mt] = *reinterpret_cast<const bf16x8*>(&xs[mt * 16 + lr][ks * 32 + lg * 8]);
        #pragma unroll
        for (int t = 0; t < 3; ++t) {
            if (t < 2 || wave < 4) {
                const int nt = t * 8 + wave;
                bf16x8 bfr = *reinterpret_cast<const bf16x8*>(&Bb[nt * 16 + lr][lg * 8]);
                #pragma unroll
                for (int mt = 0; mt < 5; ++mt)
                    acc[mt][t] = __builtin_amdgcn_mfma_f32_16x16x32_bf16(af[mt], bfr, acc[mt][t], 0, 0, 0);
            }
        }
    }

    // write q tile
    #pragma unroll
    for (int t = 0; t < 3; ++t) {
        if (t < 2 || wave < 4) {
            const int col = (t * 8 + wave) * 16 + lr;
            #pragma unroll
            for (int mt = 0; mt < 5; ++mt)
                #pragma unroll
                for (int r = 0; r < 4; ++r)
                    qs[mt * 16 + lg * 4 + r][col] = f2b(acc[mt][t][r]);
        }
    }
    __syncthreads();

    // ---- per-bs finish: waves 0..3, bs-local ----
    if (wave < 4) {
        const int b = wave;
        const int rA0 = b * 20 + lr;
        int rA1 = b * 20 + 16 + lr; if (rA1 > 79) rA1 = 79;

        f32x4 s[2][2] = {};
        for (int ks = 0; ks < 10; ++ks) {
            bf16x8 a0 = *reinterpret_cast<const bf16x8*>(&qs[rA0][ks * 32 + lg * 8]);
            bf16x8 a1 = *reinterpret_cast<const bf16x8*>(&qs[rA1][ks * 32 + lg * 8]);
            bf16x8 b0 = *reinterpret_cast<const bf16x8*>(&xs[rA0][ks * 32 + lg * 8]);
            bf16x8 b1 = *reinterpret_cast<const bf16x8*>(&xs[rA1][ks * 32 + lg * 8]);
            s[0][0] = __builtin_amdgcn_mfma_f32_16x16x32_bf16(a0, b0, s[0][0], 0, 0, 0);
            s[0][1] = __builtin_amdgcn_mfma_f32_16x16x32_bf16(a0, b1, s[0][1], 0, 0, 0);
            s[1][0] = __builtin_amdgcn_mfma_f32_16x16x32_bf16(a1, b0, s[1][0], 0, 0, 0);
            s[1][1] = __builtin_amdgcn_mfma_f32_16x16x32_bf16(a1, b1, s[1][1], 0, 0, 0);
        }

        // in-register softmax over m (cols). row l = mt*16+lg*4+r; col m = nt*16+lr.
        const float scl = 0.057735026918962584f;  // 1/sqrt(300)
        #pragma unroll
        for (int mt = 0; mt < 2; ++mt) {
            #pragma unroll
            for (int r = 0; r < 4; ++r) {
                float v0 = s[mt][0][r] * scl;
                float v1 = s[mt][1][r] * scl;
                float mx = (lr < 4) ? fmaxf(v0, v1) : v0;
                mx = fmaxf(mx, __shfl_xor(mx, 1));
                mx = fmaxf(mx, __shfl_xor(mx, 2));
                mx = fmaxf(mx, __shfl_xor(mx, 4));
                mx = fmaxf(mx, __shfl_xor(mx, 8));
                float e0 = __expf(v0 - mx);
                float e1 = (lr < 4) ? __expf(v1 - mx) : 0.f;
                float sm = e0 + e1;
                sm += __shfl_xor(sm, 1);
                sm += __shfl_xor(sm, 2);
                sm += __shfl_xor(sm, 4);
                sm += __shfl_xor(sm, 8);
                const float inv = 1.f / sm;
                const int row = mt * 16 + lg * 4 + r;
                if (row < LL) {
                    atw[b][row][lr]      = f2b(e0 * inv);
                    atw[b][row][16 + lr] = f2b(e1 * inv);   // lr>=4 writes 0
                }
            }
        }

        // v = attn * xv_n  (B-frag built from global xv)
        bf16x8 bv;
        #pragma unroll
        for (int j = 0; j < 8; ++j) {
            int m = lg * 8 + j; if (m > 19) m = 19;   // attn cols >=20 are zero
            bv[j] = xv[(row0 + b * 20 + m) * 256 + n * 16 + lr];
        }
        bf16x8 va0 = *reinterpret_cast<const bf16x8*>(&atw[b][lr][lg * 8]);
        bf16x8 va1 = *reinterpret_cast<const bf16x8*>(&atw[b][16 + lr][lg * 8]);
        f32x4 z = {0.f, 0.f, 0.f, 0.f};
        f32x4 v0 = __builtin_amdgcn_mfma_f32_16x16x32_bf16(va0, bv, z, 0, 0, 0);
        f32x4 v1 = __builtin_amdgcn_mfma_f32_16x16x32_bf16(va1, bv, z, 0, 0, 0);
        #pragma unroll
        for (int r = 0; r < 4; ++r) {
            int row = lg * 4 + r;
            out1[(row0 + b * 20 + row) * 256 + n * 16 + lr] = v0[r];  // rows 0..15 valid
            int row1 = 16 + lg * 4 + r;
            if (row1 < LL)
                out1[(row0 + b * 20 + row1) * 256 + n * 16 + lr] = v1[r];
        }
    }
}

// ---------------------------------------------------------------------------
// Additive attention pooling per bs, MFMA add_key. grid 1600, block 256.
// ---------------------------------------------------------------------------
__global__ __launch_bounds__(256) void nrms_pool_mfma(
    const float* __restrict__ out1,
    const short* __restrict__ kwb,    // [208][256] bf16
    const float* __restrict__ keyB,   // [200]
    const float* __restrict__ query,  // [200]
    float*       __restrict__ out2)   // [NBS][256]
{
    const int bs   = blockIdx.x;
    const int tid  = threadIdx.x;
    const int wave = tid >> 6;
    const int lane = tid & 63;
    const int lr   = lane & 15;
    const int lg   = lane >> 4;

    __shared__ float mh[LL][257];
    __shared__ short mhb[32][266];
    __shared__ float s2p[32];

    for (int i = tid; i < 12 * 128; i += 256) {
        const int r = 20 + i / 128, c = (i % 128) * 2;
        *reinterpret_cast<int*>(&mhb[r][c]) = 0;
    }
    if (tid < 32) s2p[tid] = 0.f;

    for (int idx = tid; idx < LL * 64; idx += 256) {
        const int l = idx >> 6, h4 = (idx & 63) * 4;
        const float4 v = *reinterpret_cast<const float4*>(out1 + ((size_t)bs * LL + l) * HID + h4);
        mh[l][h4] = v.x; mh[l][h4 + 1] = v.y; mh[l][h4 + 2] = v.z; mh[l][h4 + 3] = v.w;
        mhb[l][h4] = f2b(v.x); mhb[l][h4 + 1] = f2b(v.y);
        mhb[l][h4 + 2] = f2b(v.z); mhb[l][h4 + 3] = f2b(v.w);
    }
    __syncthreads();

    for (int t = wave; t < 26; t += 4) {
        const int mt = t & 1, nt = t >> 1;
        f32x4 acc = {0.f, 0.f, 0.f, 0.f};
        const short* ap = &mhb[mt * 16 + lr][lg * 8];
        const short* bp = kwb + (nt * 16 + lr) * 256 + lg * 8;
        #pragma unroll
        for (int k = 0; k < 8; ++k) {
            bf16x8 a = *reinterpret_cast<const bf16x8*>(ap + k * 32);
            bf16x8 b = *reinterpret_cast<const bf16x8*>(bp + k * 32);
            acc = __builtin_amdgcn_mfma_f32_16x16x32_bf16(a, b, acc, 0, 0, 0);
        }
        const int d = nt * 16 + lr;
        const float qd = (d < QD) ? query[d] : 0.f;
        const float kb = (d < QD) ? keyB[d] : 0.f;
        float vals[4];
        #pragma unroll
        for (int r = 0; r < 4; ++r) vals[r] = qd * ftanh(acc[r] + kb);
        #pragma unroll
        for (int off = 1; off < 16; off <<= 1) {
            #pragma unroll
            for (int r = 0; r < 4; ++r) vals[r] += __shfl_xor(vals[r], off);
        }
        if (lr == 0) {
            #pragma unroll
            for (int r = 0; r < 4; ++r)
                atomicAdd(&s2p[mt * 16 + lg * 4 + r], vals[r]);
        }
    }
    __syncthreads();

    if (tid == 0) {
        float mx = -1e30f;
        #pragma unroll
        for (int l = 0; l < LL; ++l) mx = fmaxf(mx, s2p[l] * 0.07071067811865475f);
        float sum = 0.f;
        float e[LL];
        #pragma unroll
        for (int l = 0; l < LL; ++l) { e[l] = __expf(s2p[l] * 0.07071067811865475f - mx); sum += e[l]; }
        const float inv = 1.f / sum;
        #pragma unroll
        for (int l = 0; l < LL; ++l) s2p[l] = e[l] * inv;
    }
    __syncthreads();

    {
        const int h = tid;
        float acc = 0.f;
        #pragma unroll
        for (int l = 0; l < LL; ++l) acc = fmaf(s2p[l], mh[l][h], acc);
        out2[(size_t)bs * HID + h] = acc;
    }
}

// ===========================================================================
// FALLBACK PATH (round-3, needs only 3.4 MB ws) — used if ws_size too small
// ===========================================================================

#define XP 330
#define TP 42
#define AP 34

__global__ __launch_bounds__(1024) void transpose_qw(
    const float* __restrict__ qW, short* __restrict__ wqt)
{
    __shared__ float t[32][33];
    const int n = blockIdx.z;
    const int e0 = blockIdx.x * 32, f0 = blockIdx.y * 32;
    const int tx = threadIdx.x, ty = threadIdx.y;
    const int e = e0 + ty, f = f0 + tx;
    t[ty][tx] = (e < EE && f < EE) ? qW[(size_t)n * EE * EE + e * EE + f] : 0.f;
    __syncthreads();
    const int fo = f0 + ty, eo = e0 + tx;
    if (fo < 304)
        wqt[(size_t)n * 304 * 320 + fo * 320 + eo] = f2b(t[tx][ty]);
}

__global__ void conv_vw(const float* __restrict__ vW, short* __restrict__ wvt) {
    int idx = blockIdx.x * 256 + threadIdx.x;
    if (idx >= NH * VD * 320) return;
    int e = idx % 320;
    int v = (idx / 320) % VD;
    int n = idx / (320 * VD);
    wvt[idx] = (e < EE) ? f2b(vW[(size_t)n * EE * VD + e * VD + v]) : (short)0;
}

__global__ __launch_bounds__(512) void nrms_attn_mfma(
    const int*   __restrict__ news,
    const float* __restrict__ emb,
    const short* __restrict__ wqt,
    const float* __restrict__ qB,
    const short* __restrict__ wvt,
    const float* __restrict__ vB,
    float*       __restrict__ out1)
{
    const int bs   = blockIdx.x;
    const int tid  = threadIdx.x;
    const int wave = tid >> 6;
    const int lane = tid & 63;
    const int lr   = lane & 15;
    const int lg   = lane >> 4;

    __shared__ short xs[32][XP];
    __shared__ short xT[320][TP];
    __shared__ short qs[32][XP];
    __shared__ float sc[32][33];
    __shared__ short at[32][AP];

    {
        int* z = (int*)&xs[0][0];
        for (int i = tid; i < 32 * XP / 2; i += 512) z[i] = 0;
        z = (int*)&qs[0][0];
        for (int i = tid; i < 32 * XP / 2; i += 512) z[i] = 0;
        z = (int*)&xT[0][0];
        for (int i = tid; i < 320 * TP / 2; i += 512) z[i] = 0;
    }
    __syncthreads();

    for (int idx = tid; idx < LL * 75; idx += 512) {
        const int l = idx / 75, e4 = (idx % 75) * 4;
        const int row = news[bs * LL + l];
        const float4 v = *reinterpret_cast<const float4*>(emb + (size_t)row * EE + e4);
        const short b0 = f2b(v.x), b1 = f2b(v.y), b2 = f2b(v.z), b3 = f2b(v.w);
        xs[l][e4] = b0; xs[l][e4 + 1] = b1; xs[l][e4 + 2] = b2; xs[l][e4 + 3] = b3;
        xT[e4][l] = b0; xT[e4 + 1][l] = b1; xT[e4 + 2][l] = b2; xT[e4 + 3][l] = b3;
    }
    __syncthreads();

    for (int n = 0; n < NH; ++n) {
        const short* wq = wqt + (size_t)n * 304 * 320;

        for (int p = wave; p < 19; p += 8) {
            f32x4 acc0 = {0.f, 0.f, 0.f, 0.f};
            f32x4 acc1 = {0.f, 0.f, 0.f, 0.f};
            const short* a0p = &xs[lr][lg * 8];
            const short* a1p = &xs[16 + lr][lg * 8];
            const short* bp  = wq + (p * 16 + lr) * 320 + lg * 8;
            #pragma unroll
            for (int k = 0; k < 10; ++k) {
                bf16x8 b  = *reinterpret_cast<const bf16x8*>(bp + k * 32);
                bf16x8 a0 = *reinterpret_cast<const bf16x8*>(a0p + k * 32);
                bf16x8 a1 = *reinterpret_cast<const bf16x8*>(a1p + k * 32);
                acc0 = __builtin_amdgcn_mfma_f32_16x16x32_bf16(a0, b, acc0, 0, 0, 0);
                acc1 = __builtin_amdgcn_mfma_f32_16x16x32_bf16(a1, b, acc1, 0, 0, 0);
            }
            const int col = p * 16 + lr;
            const float bias = (col < EE) ? qB[n * EE + col] : 0.f;
            #pragma unroll
            for (int r = 0; r < 4; ++r) {
                qs[lg * 4 + r][col]      = f2b(acc0[r] + bias);
                qs[16 + lg * 4 + r][col] = f2b(acc1[r] + bias);
            }
        }
        __syncthreads();

        if (wave < 4) {
            const int mt = wave & 1, nt = wave >> 1;
            f32x4 acc = {0.f, 0.f, 0.f, 0.f};
            const short* ap = &qs[mt * 16 + lr][lg * 8];
            const short* bp = &xs[nt * 16 + lr][lg * 8];
            #pragma unroll
            for (int k = 0; k < 10; ++k) {
                bf16x8 a = *reinterpret_cast<const bf16x8*>(ap + k * 32);
                bf16x8 b = *reinterpret_cast<const bf16x8*>(bp + k * 32);
                acc = __builtin_amdgcn_mfma_f32_16x16x32_bf16(a, b, acc, 0, 0, 0);
            }
            #pragma unroll
            for (int r = 0; r < 4; ++r)
                sc[mt * 16 + lg * 4 + r][nt * 16 + lr] = acc[r] * 0.057735026918962584f;
        }
        __syncthreads();

        if (tid < LL) {
            float mx = -1e30f;
            #pragma unroll
            for (int m = 0; m < LL; ++m) mx = fmaxf(mx, sc[tid][m]);
            float ev[LL], sum = 0.f;
            #pragma unroll
            for (int m = 0; m < LL; ++m) { ev[m] = __expf(sc[tid][m] - mx); sum += ev[m]; }
            const float inv = 1.f / sum;
            #pragma unroll
            for (int m = 0; m < LL; ++m) at[tid][m] = f2b(ev[m] * inv);
            #pragma unroll
            for (int m = LL; m < 32; ++m) at[tid][m] = 0;
        } else if (tid < 32) {
            int* zr = (int*)&at[tid][0];
            #pragma unroll
            for (int m = 0; m < 16; ++m) zr[m] = 0;
        }
        __syncthreads();

        for (int p = wave; p < 19; p += 8) {
            bf16x8 b  = *reinterpret_cast<const bf16x8*>(&xT[p * 16 + lr][lg * 8]);
            bf16x8 a0 = *reinterpret_cast<const bf16x8*>(&at[lr][lg * 8]);
            bf16x8 a1 = *reinterpret_cast<const bf16x8*>(&at[16 + lr][lg * 8]);
            f32x4 z = {0.f, 0.f, 0.f, 0.f};
            f32x4 c0 = __builtin_amdgcn_mfma_f32_16x16x32_bf16(a0, b, z, 0, 0, 0);
            f32x4 c1 = __builtin_amdgcn_mfma_f32_16x16x32_bf16(a1, b, z, 0, 0, 0);
            const int col = p * 16 + lr;
            #pragma unroll
            for (int r = 0; r < 4; ++r) {
                qs[lg * 4 + r][col]      = f2b(c0[r]);
                qs[16 + lg * 4 + r][col] = f2b(c1[r]);
            }
        }
        __syncthreads();

        if (wave < 2) {
            const int mt = wave;
            f32x4 acc = {0.f, 0.f, 0.f, 0.f};
            const short* ap = &qs[mt * 16 + lr][lg * 8];
            const short* bp = wvt + (size_t)n * VD * 320 + lr * 320 + lg * 8;
            #pragma unroll
            for (int k = 0; k < 10; ++k) {
                bf16x8 a = *reinterpret_cast<const bf16x8*>(ap + k * 32);
                bf16x8 b = *reinterpret_cast<const bf16x8*>(bp + k * 32);
                acc = __builtin_amdgcn_mfma_f32_16x16x32_bf16(a, b, acc, 0, 0, 0);
            }
            #pragma unroll
            for (int r = 0; r < 4; ++r) {
                const int row = mt * 16 + lg * 4 + r;
                if (row < LL)
                    out1[((size_t)bs * LL + row) * HID + n * VD + lr] = acc[r] + vB[n * VD + lr];
            }
        }
        __syncthreads();
    }
}

// ===========================================================================

extern "C" void kernel_launch(void* const* d_in, const int* in_sizes, int n_in,
                              void* d_out, int out_size, void* d_ws, size_t ws_size,
                              hipStream_t stream) {
    const int*   news  = (const int*)d_in[0];
    const float* emb   = (const float*)d_in[1];
    const float* qW    = (const float*)d_in[2];
    const float* qB    = (const float*)d_in[3];
    const float* vW    = (const float*)d_in[4];
    const float* vB    = (const float*)d_in[5];
    const float* keyW  = (const float*)d_in[6];
    const float* keyB  = (const float*)d_in[7];
    const float* query = (const float*)d_in[8];

    float* out1 = (float*)d_out;            // news_embedding: 8192000 floats
    float* out2 = out1 + 8192000;           // news_repr: 409600 floats

    const size_t NEED = ((size_t)10240000 + 1638400 + 81920 + 8192000 + 53248) * 2;

    if (ws_size >= NEED) {
        short* Xb  = (short*)d_ws;                  // 32000*320
        short* WqT = Xb + 10240000;                 // 16*320*320
        short* WvT = WqT + 1638400;                 // 256*320
        short* xv  = WvT + 81920;                   // 32000*256
        short* kwb = xv + 8192000;                  // 208*256

        hipLaunchKernelGGL(build_xb, dim3(10000), dim3(256), 0, stream, news, emb, Xb);
        hipLaunchKernelGGL(build_wqt, dim3(10, 10, 16), dim3(32, 32), 0, stream, qW, qB, WqT);
        hipLaunchKernelGGL(build_wvt, dim3(320), dim3(256), 0, stream, vW, vB, WvT);
        hipLaunchKernelGGL(conv_kw, dim3(208), dim3(256), 0, stream, keyW, kwb);
        hipLaunchKernelGGL(gemm_xv, dim3(2, 250), dim3(256), 0, stream, Xb, WvT, xv);
        hipLaunchKernelGGL(qattn, dim3(400, 16), dim3(512), 0, stream, Xb, WqT, xv, out1);
        hipLaunchKernelGGL(nrms_pool_mfma, dim3(NBS), dim3(256), 0, stream,
                           out1, kwb, keyB, query, out2);
    } else {
        short* wqt = (short*)d_ws;
        short* wvt = wqt + (size_t)NH * 304 * 320;
        short* kwb = wvt + (size_t)NH * VD * 320;

        hipLaunchKernelGGL(transpose_qw, dim3(10, 10, 16), dim3(32, 32), 0, stream, qW, wqt);
        hipLaunchKernelGGL(conv_vw, dim3(320), dim3(256), 0, stream, vW, wvt);
        hipLaunchKernelGGL(conv_kw, dim3(208), dim3(256), 0, stream, keyW, kwb);
        hipLaunchKernelGGL(nrms_attn_mfma, dim3(NBS), dim3(512), 0, stream,
                           news, emb, wqt, qB, wvt, vB, out1);
        hipLaunchKernelGGL(nrms_pool_mfma, dim3(NBS), dim3(256), 0, stream,
                           out1, kwb, keyB, query, out2);
    }
}

// Round 5
// 423.137 us; speedup vs baseline: 7.0280x; 1.0200x over previous
//
#include <hip/hip_runtime.h>
#include <math.h>

#define NBS 1600      // B*S
#define LL 20
#define EE 300
#define NH 16
#define VD 16
#define HID 256
#define QD 200

typedef short bf16x8 __attribute__((ext_vector_type(8)));
typedef float f32x4 __attribute__((ext_vector_type(4)));

__device__ __forceinline__ short f2b(float f) {
    union { float f; unsigned u; } c; c.f = f;
    unsigned r = (c.u + 0x7FFFu + ((c.u >> 16) & 1u)) >> 16;  // RNE
    return (short)r;
}

__device__ __forceinline__ float ftanh(float a) {
    a = fminf(fmaxf(a, -15.f), 15.f);
    float t = __expf(2.f * a);
    return (t - 1.f) / (t + 1.f);
}

// ===========================================================================
// NEW PATH (needs ~40.4 MB ws)
// ===========================================================================

// news/emb -> Xb bf16 [32000][320]; col300 = 1.0 (bias channel), 301..319 = 0
__global__ void build_xb(const int* __restrict__ news, const float* __restrict__ emb,
                         short* __restrict__ Xb) {
    int idx = blockIdx.x * 256 + threadIdx.x;     // one per 4 elems
    if (idx >= 32000 * 80) return;
    int i = idx / 80, e4 = (idx % 80) * 4;
    short4 o;
    if (e4 < 300) {
        const float4 v = *reinterpret_cast<const float4*>(emb + (size_t)news[i] * EE + e4);
        o.x = f2b(v.x); o.y = f2b(v.y); o.z = f2b(v.z); o.w = f2b(v.w);
    } else if (e4 == 300) {
        o.x = (short)0x3F80; o.y = 0; o.z = 0; o.w = 0;
    } else {
        o.x = o.y = o.z = o.w = 0;
    }
    *reinterpret_cast<short4*>(Xb + (size_t)i * 320 + e4) = o;
}

// Wq [n][e][f] -> WqT bf16 [n][f(320)][e(320)], col300 = qB, zero rows f>=300
__global__ __launch_bounds__(1024) void build_wqt(
    const float* __restrict__ qW, const float* __restrict__ qB, short* __restrict__ WqT)
{
    __shared__ float t[32][33];
    const int n = blockIdx.z;
    const int e0 = blockIdx.x * 32, f0 = blockIdx.y * 32;
    const int tx = threadIdx.x, ty = threadIdx.y;
    const int e = e0 + ty, f = f0 + tx;
    t[ty][tx] = (e < EE && f < EE) ? qW[((size_t)n * EE + e) * EE + f] : 0.f;
    __syncthreads();
    const int fo = f0 + ty, eo = e0 + tx;
    float val;
    if (fo >= EE)      val = 0.f;
    else if (eo < EE)  val = t[tx][ty];
    else if (eo == EE) val = qB[n * EE + fo];
    else               val = 0.f;
    WqT[((size_t)n * 320 + fo) * 320 + eo] = f2b(val);
}

// Wv [n][e][v] -> WvT bf16 [256][320] rows c=n*16+vd, col300 = vB
__global__ void build_wvt(const float* __restrict__ vW, const float* __restrict__ vB,
                          short* __restrict__ WvT) {
    int idx = blockIdx.x * 256 + threadIdx.x;
    if (idx >= 256 * 320) return;
    int c = idx / 320, e = idx % 320;
    int n = c >> 4, vd = c & 15;
    float val = (e < EE) ? vW[((size_t)n * EE + e) * VD + vd]
                         : (e == EE ? vB[n * VD + vd] : 0.f);
    WvT[idx] = f2b(val);
}

// keyW [200][256] fp32 -> bf16 [208][256] (rows >=200 zero)
__global__ void conv_kw(const float* __restrict__ keyW, short* __restrict__ kwb) {
    int idx = blockIdx.x * 256 + threadIdx.x;
    if (idx >= 208 * 256) return;
    int d = idx >> 8;
    kwb[idx] = (d < QD) ? f2b(keyW[idx]) : (short)0;
}

// xv = Xb * WvT^T : [32000][256] bf16.  128x128 tile, 4 waves.
__global__ __launch_bounds__(256) void gemm_xv(
    const short* __restrict__ Xb, const short* __restrict__ WvT, short* __restrict__ xv)
{
    const int nt0 = blockIdx.x * 128;
    const size_t mt0 = (size_t)blockIdx.y * 128;
    const int tid = threadIdx.x, wave = tid >> 6, lane = tid & 63;
    const int lr = lane & 15, lg = lane >> 4;
    const int wm = wave & 1, wn = wave >> 1;

    __shared__ short As[128][66];
    __shared__ short Bs[128][66];
    f32x4 acc[4][4] = {};

    for (int ks = 0; ks < 5; ++ks) {
        __syncthreads();
        for (int u = 0; u < 4; ++u) {
            int idx = u * 256 + tid;          // 0..1023
            int rr = idx >> 3, c8 = idx & 7;
            *reinterpret_cast<bf16x8*>(&As[rr][c8 * 8]) =
                *reinterpret_cast<const bf16x8*>(Xb + (mt0 + rr) * 320 + ks * 64 + c8 * 8);
            *reinterpret_cast<bf16x8*>(&Bs[rr][c8 * 8]) =
                *reinterpret_cast<const bf16x8*>(WvT + (size_t)(nt0 + rr) * 320 + ks * 64 + c8 * 8);
        }
        __syncthreads();
        #pragma unroll
        for (int kk = 0; kk < 2; ++kk) {
            bf16x8 af[4], bfv[4];
            #pragma unroll
            for (int f = 0; f < 4; ++f)
                af[f] = *reinterpret_cast<const bf16x8*>(&As[wm * 64 + f * 16 + lr][kk * 32 + lg * 8]);
            #pragma unroll
            for (int f = 0; f < 4; ++f)
                bfv[f] = *reinterpret_cast<const bf16x8*>(&Bs[wn * 64 + f * 16 + lr][kk * 32 + lg * 8]);
            #pragma unroll
            for (int i = 0; i < 4; ++i)
                #pragma unroll
                for (int j = 0; j < 4; ++j)
                    acc[i][j] = __builtin_amdgcn_mfma_f32_16x16x32_bf16(af[i], bfv[j], acc[i][j], 0, 0, 0);
        }
    }
    #pragma unroll
    for (int i = 0; i < 4; ++i)
        #pragma unroll
        for (int j = 0; j < 4; ++j)
            #pragma unroll
            for (int r = 0; r < 4; ++r)
                xv[(mt0 + wm * 64 + i * 16 + lg * 4 + r) * 256 + nt0 + wn * 64 + j * 16 + lr]
                    = f2b(acc[i][j][r]);
}

// ---------------------------------------------------------------------------
// qattn v2: one block per (group of 2 bs, head). 512 threads (8 waves).
// q-GEMM M=48(40 real) x N=320 x K=320 with B-frags straight from L2 (no LDS
// staging, no inner barriers, manual 1-deep A/B pipeline). LDS 62.4 KB ->
// 2 blocks/CU (4 waves/SIMD).
// ---------------------------------------------------------------------------
__global__ __launch_bounds__(512, 4) void qattn(
    const short* __restrict__ Xb,    // [32000][320]
    const short* __restrict__ WqT,   // [16][320][320]
    const short* __restrict__ xv,    // [32000][256]
    float*       __restrict__ out1)  // [32000][256]
{
    const int g = blockIdx.x;        // group of 2 bs
    const int n = blockIdx.y;        // head
    const int tid = threadIdx.x, wave = tid >> 6, lane = tid & 63;
    const int lr = lane & 15, lg = lane >> 4;
    const size_t row0 = (size_t)g * 40;

    __shared__ short xs[48][330];    // rows 40..47 zero
    __shared__ short qs[40][330];
    __shared__ short atw[2][32][34]; // per-bs attn (pads zero)

    // zero atw + xs pad rows
    for (int i = tid; i < 1088; i += 512) reinterpret_cast<int*>(atw)[i] = 0;
    for (int i = tid; i < 1320; i += 512) reinterpret_cast<int*>(&xs[40][0])[i] = 0;

    // load xs: 40 rows x 320 cols
    for (int idx = tid; idx < 1600; idx += 512) {
        int l = idx / 40, c8 = idx % 40;
        *reinterpret_cast<bf16x8*>(&xs[l][c8 * 8]) =
            *reinterpret_cast<const bf16x8*>(Xb + (row0 + l) * 320 + c8 * 8);
    }
    __syncthreads();

    const short* wh = WqT + (size_t)n * 320 * 320;
    // tile map: ti=0 -> nt=wave; ti=1 -> nt=8+wave; ti=2 -> nt=16+(wave-4), wave>=4
    const bool has2 = (wave >= 4);
    const int nt0r = wave * 16 + lr;
    const int nt1r = (8 + wave) * 16 + lr;
    const int nt2r = (16 + (wave - 4)) * 16 + lr;

    f32x4 acc[3][3] = {};
    bf16x8 bcur[3], acur[3], bnxt[3], anxt[3];
    bcur[0] = *reinterpret_cast<const bf16x8*>(wh + (size_t)nt0r * 320 + lg * 8);
    bcur[1] = *reinterpret_cast<const bf16x8*>(wh + (size_t)nt1r * 320 + lg * 8);
    if (has2) bcur[2] = *reinterpret_cast<const bf16x8*>(wh + (size_t)nt2r * 320 + lg * 8);
    #pragma unroll
    for (int mt = 0; mt < 3; ++mt)
        acur[mt] = *reinterpret_cast<const bf16x8*>(&xs[mt * 16 + lr][lg * 8]);

    for (int ks = 0; ks < 10; ++ks) {
        if (ks < 9) {
            const int kc = (ks + 1) * 32 + lg * 8;
            bnxt[0] = *reinterpret_cast<const bf16x8*>(wh + (size_t)nt0r * 320 + kc);
            bnxt[1] = *reinterpret_cast<const bf16x8*>(wh + (size_t)nt1r * 320 + kc);
            if (has2) bnxt[2] = *reinterpret_cast<const bf16x8*>(wh + (size_t)nt2r * 320 + kc);
            #pragma unroll
            for (int mt = 0; mt < 3; ++mt)
                anxt[mt] = *reinterpret_cast<const bf16x8*>(&xs[mt * 16 + lr][kc]);
        }
        #pragma unroll
        for (int mt = 0; mt < 3; ++mt) {
            acc[mt][0] = __builtin_amdgcn_mfma_f32_16x16x32_bf16(acur[mt], bcur[0], acc[mt][0], 0, 0, 0);
            acc[mt][1] = __builtin_amdgcn_mfma_f32_16x16x32_bf16(acur[mt], bcur[1], acc[mt][1], 0, 0, 0);
        }
        if (has2) {
            #pragma unroll
            for (int mt = 0; mt < 3; ++mt)
                acc[mt][2] = __builtin_amdgcn_mfma_f32_16x16x32_bf16(acur[mt], bcur[2], acc[mt][2], 0, 0, 0);
        }
        #pragma unroll
        for (int t = 0; t < 3; ++t) { acur[t] = anxt[t]; bcur[t] = bnxt[t]; }
    }

    // write q tile (rows < 40)
    #pragma unroll
    for (int ti = 0; ti < 3; ++ti) {
        if (ti < 2 || has2) {
            const int col = (ti < 2) ? (ti * 8 + wave) * 16 + lr : (16 + (wave - 4)) * 16 + lr;
            #pragma unroll
            for (int mt = 0; mt < 3; ++mt)
                #pragma unroll
                for (int r = 0; r < 4; ++r) {
                    const int row = mt * 16 + lg * 4 + r;
                    if (row < 40) qs[row][col] = f2b(acc[mt][ti][r]);
                }
        }
    }
    __syncthreads();

    // ---- per-bs finish on waves 0,1 ----
    if (wave < 2) {
        const int b = wave;
        const int rA0 = b * 20 + lr;
        int rc = b * 20 + 16 + lr; if (rc > 39) rc = 39;
        const int rA1 = rc;

        f32x4 s[2][2] = {};
        for (int ks = 0; ks < 10; ++ks) {
            const int kc = ks * 32 + lg * 8;
            bf16x8 a0 = *reinterpret_cast<const bf16x8*>(&qs[rA0][kc]);
            bf16x8 a1 = *reinterpret_cast<const bf16x8*>(&qs[rA1][kc]);
            bf16x8 b0 = *reinterpret_cast<const bf16x8*>(&xs[rA0][kc]);
            bf16x8 b1 = *reinterpret_cast<const bf16x8*>(&xs[rA1][kc]);
            s[0][0] = __builtin_amdgcn_mfma_f32_16x16x32_bf16(a0, b0, s[0][0], 0, 0, 0);
            s[0][1] = __builtin_amdgcn_mfma_f32_16x16x32_bf16(a0, b1, s[0][1], 0, 0, 0);
            s[1][0] = __builtin_amdgcn_mfma_f32_16x16x32_bf16(a1, b0, s[1][0], 0, 0, 0);
            s[1][1] = __builtin_amdgcn_mfma_f32_16x16x32_bf16(a1, b1, s[1][1], 0, 0, 0);
        }

        // in-register softmax over cols m. D: row = mt*16+lg*4+r, col m = nt*16+lr.
        const float scl = 0.057735026918962584f;  // 1/sqrt(300)
        #pragma unroll
        for (int mt = 0; mt < 2; ++mt) {
            #pragma unroll
            for (int r = 0; r < 4; ++r) {
                float v0 = s[mt][0][r] * scl;
                float v1 = s[mt][1][r] * scl;
                float mx = (lr < 4) ? fmaxf(v0, v1) : v0;
                mx = fmaxf(mx, __shfl_xor(mx, 1));
                mx = fmaxf(mx, __shfl_xor(mx, 2));
                mx = fmaxf(mx, __shfl_xor(mx, 4));
                mx = fmaxf(mx, __shfl_xor(mx, 8));
                float e0 = __expf(v0 - mx);
                float e1 = (lr < 4) ? __expf(v1 - mx) : 0.f;
                float sm = e0 + e1;
                sm += __shfl_xor(sm, 1);
                sm += __shfl_xor(sm, 2);
                sm += __shfl_xor(sm, 4);
                sm += __shfl_xor(sm, 8);
                const float inv = 1.f / sm;
                const int row = mt * 16 + lg * 4 + r;
                if (row < LL) {
                    atw[b][row][lr]      = f2b(e0 * inv);
                    atw[b][row][16 + lr] = f2b(e1 * inv);   // lr>=4 writes 0
                }
            }
        }

        // v = attn * xv_n
        bf16x8 bv;
        #pragma unroll
        for (int j = 0; j < 8; ++j) {
            int m = lg * 8 + j; if (m > 19) m = 19;   // attn cols >=20 are zero
            bv[j] = xv[(row0 + b * 20 + m) * 256 + n * 16 + lr];
        }
        bf16x8 va0 = *reinterpret_cast<const bf16x8*>(&atw[b][lr][lg * 8]);
        bf16x8 va1 = *reinterpret_cast<const bf16x8*>(&atw[b][16 + lr][lg * 8]);
        f32x4 z = {0.f, 0.f, 0.f, 0.f};
        f32x4 v0 = __builtin_amdgcn_mfma_f32_16x16x32_bf16(va0, bv, z, 0, 0, 0);
        f32x4 v1 = __builtin_amdgcn_mfma_f32_16x16x32_bf16(va1, bv, z, 0, 0, 0);
        #pragma unroll
        for (int r = 0; r < 4; ++r) {
            int row = lg * 4 + r;
            out1[(row0 + b * 20 + row) * 256 + n * 16 + lr] = v0[r];
            int row1 = 16 + lg * 4 + r;
            if (row1 < LL)
                out1[(row0 + b * 20 + row1) * 256 + n * 16 + lr] = v1[r];
        }
    }
}

// ---------------------------------------------------------------------------
// Additive attention pooling per bs, MFMA add_key. grid 1600, block 256.
// ---------------------------------------------------------------------------
__global__ __launch_bounds__(256) void nrms_pool_mfma(
    const float* __restrict__ out1,
    const short* __restrict__ kwb,    // [208][256] bf16
    const float* __restrict__ keyB,   // [200]
    const float* __restrict__ query,  // [200]
    float*       __restrict__ out2)   // [NBS][256]
{
    const int bs   = blockIdx.x;
    const int tid  = threadIdx.x;
    const int wave = tid >> 6;
    const int lane = tid & 63;
    const int lr   = lane & 15;
    const int lg   = lane >> 4;

    __shared__ float mh[LL][257];
    __shared__ short mhb[32][266];
    __shared__ float s2p[32];

    for (int i = tid; i < 12 * 128; i += 256) {
        const int r = 20 + i / 128, c = (i % 128) * 2;
        *reinterpret_cast<int*>(&mhb[r][c]) = 0;
    }
    if (tid < 32) s2p[tid] = 0.f;

    for (int idx = tid; idx < LL * 64; idx += 256) {
        const int l = idx >> 6, h4 = (idx & 63) * 4;
        const float4 v = *reinterpret_cast<const float4*>(out1 + ((size_t)bs * LL + l) * HID + h4);
        mh[l][h4] = v.x; mh[l][h4 + 1] = v.y; mh[l][h4 + 2] = v.z; mh[l][h4 + 3] = v.w;
        mhb[l][h4] = f2b(v.x); mhb[l][h4 + 1] = f2b(v.y);
        mhb[l][h4 + 2] = f2b(v.z); mhb[l][h4 + 3] = f2b(v.w);
    }
    __syncthreads();

    for (int t = wave; t < 26; t += 4) {
        const int mt = t & 1, nt = t >> 1;
        f32x4 acc = {0.f, 0.f, 0.f, 0.f};
        const short* ap = &mhb[mt * 16 + lr][lg * 8];
        const short* bp = kwb + (nt * 16 + lr) * 256 + lg * 8;
        #pragma unroll
        for (int k = 0; k < 8; ++k) {
            bf16x8 a = *reinterpret_cast<const bf16x8*>(ap + k * 32);
            bf16x8 b = *reinterpret_cast<const bf16x8*>(bp + k * 32);
            acc = __builtin_amdgcn_mfma_f32_16x16x32_bf16(a, b, acc, 0, 0, 0);
        }
        const int d = nt * 16 + lr;
        const float qd = (d < QD) ? query[d] : 0.f;
        const float kb = (d < QD) ? keyB[d] : 0.f;
        float vals[4];
        #pragma unroll
        for (int r = 0; r < 4; ++r) vals[r] = qd * ftanh(acc[r] + kb);
        #pragma unroll
        for (int off = 1; off < 16; off <<= 1) {
            #pragma unroll
            for (int r = 0; r < 4; ++r) vals[r] += __shfl_xor(vals[r], off);
        }
        if (lr == 0) {
            #pragma unroll
            for (int r = 0; r < 4; ++r)
                atomicAdd(&s2p[mt * 16 + lg * 4 + r], vals[r]);
        }
    }
    __syncthreads();

    if (tid == 0) {
        float mx = -1e30f;
        #pragma unroll
        for (int l = 0; l < LL; ++l) mx = fmaxf(mx, s2p[l] * 0.07071067811865475f);
        float sum = 0.f;
        float e[LL];
        #pragma unroll
        for (int l = 0; l < LL; ++l) { e[l] = __expf(s2p[l] * 0.07071067811865475f - mx); sum += e[l]; }
        const float inv = 1.f / sum;
        #pragma unroll
        for (int l = 0; l < LL; ++l) s2p[l] = e[l] * inv;
    }
    __syncthreads();

    {
        const int h = tid;
        float acc = 0.f;
        #pragma unroll
        for (int l = 0; l < LL; ++l) acc = fmaf(s2p[l], mh[l][h], acc);
        out2[(size_t)bs * HID + h] = acc;
    }
}

// ===========================================================================
// FALLBACK PATH (round-3, needs only 3.4 MB ws) — used if ws_size too small
// ===========================================================================

#define XP 330
#define TP 42
#define AP 34

__global__ __launch_bounds__(1024) void transpose_qw(
    const float* __restrict__ qW, short* __restrict__ wqt)
{
    __shared__ float t[32][33];
    const int n = blockIdx.z;
    const int e0 = blockIdx.x * 32, f0 = blockIdx.y * 32;
    const int tx = threadIdx.x, ty = threadIdx.y;
    const int e = e0 + ty, f = f0 + tx;
    t[ty][tx] = (e < EE && f < EE) ? qW[(size_t)n * EE * EE + e * EE + f] : 0.f;
    __syncthreads();
    const int fo = f0 + ty, eo = e0 + tx;
    if (fo < 304)
        wqt[(size_t)n * 304 * 320 + fo * 320 + eo] = f2b(t[tx][ty]);
}

__global__ void conv_vw(const float* __restrict__ vW, short* __restrict__ wvt) {
    int idx = blockIdx.x * 256 + threadIdx.x;
    if (idx >= NH * VD * 320) return;
    int e = idx % 320;
    int v = (idx / 320) % VD;
    int n = idx / (320 * VD);
    wvt[idx] = (e < EE) ? f2b(vW[(size_t)n * EE * VD + e * VD + v]) : (short)0;
}

__global__ __launch_bounds__(512) void nrms_attn_mfma(
    const int*   __restrict__ news,
    const float* __restrict__ emb,
    const short* __restrict__ wqt,
    const float* __restrict__ qB,
    const short* __restrict__ wvt,
    const float* __restrict__ vB,
    float*       __restrict__ out1)
{
    const int bs   = blockIdx.x;
    const int tid  = threadIdx.x;
    const int wave = tid >> 6;
    const int lane = tid & 63;
    const int lr   = lane & 15;
    const int lg   = lane >> 4;

    __shared__ short xs[32][XP];
    __shared__ short xT[320][TP];
    __shared__ short qs[32][XP];
    __shared__ float sc[32][33];
    __shared__ short at[32][AP];

    {
        int* z = (int*)&xs[0][0];
        for (int i = tid; i < 32 * XP / 2; i += 512) z[i] = 0;
        z = (int*)&qs[0][0];
        for (int i = tid; i < 32 * XP / 2; i += 512) z[i] = 0;
        z = (int*)&xT[0][0];
        for (int i = tid; i < 320 * TP / 2; i += 512) z[i] = 0;
    }
    __syncthreads();

    for (int idx = tid; idx < LL * 75; idx += 512) {
        const int l = idx / 75, e4 = (idx % 75) * 4;
        const int row = news[bs * LL + l];
        const float4 v = *reinterpret_cast<const float4*>(emb + (size_t)row * EE + e4);
        const short b0 = f2b(v.x), b1 = f2b(v.y), b2 = f2b(v.z), b3 = f2b(v.w);
        xs[l][e4] = b0; xs[l][e4 + 1] = b1; xs[l][e4 + 2] = b2; xs[l][e4 + 3] = b3;
        xT[e4][l] = b0; xT[e4 + 1][l] = b1; xT[e4 + 2][l] = b2; xT[e4 + 3][l] = b3;
    }
    __syncthreads();

    for (int n = 0; n < NH; ++n) {
        const short* wq = wqt + (size_t)n * 304 * 320;

        for (int p = wave; p < 19; p += 8) {
            f32x4 acc0 = {0.f, 0.f, 0.f, 0.f};
            f32x4 acc1 = {0.f, 0.f, 0.f, 0.f};
            const short* a0p = &xs[lr][lg * 8];
            const short* a1p = &xs[16 + lr][lg * 8];
            const short* bp  = wq + (p * 16 + lr) * 320 + lg * 8;
            #pragma unroll
            for (int k = 0; k < 10; ++k) {
                bf16x8 b  = *reinterpret_cast<const bf16x8*>(bp + k * 32);
                bf16x8 a0 = *reinterpret_cast<const bf16x8*>(a0p + k * 32);
                bf16x8 a1 = *reinterpret_cast<const bf16x8*>(a1p + k * 32);
                acc0 = __builtin_amdgcn_mfma_f32_16x16x32_bf16(a0, b, acc0, 0, 0, 0);
                acc1 = __builtin_amdgcn_mfma_f32_16x16x32_bf16(a1, b, acc1, 0, 0, 0);
            }
            const int col = p * 16 + lr;
            const float bias = (col < EE) ? qB[n * EE + col] : 0.f;
            #pragma unroll
            for (int r = 0; r < 4; ++r) {
                qs[lg * 4 + r][col]      = f2b(acc0[r] + bias);
                qs[16 + lg * 4 + r][col] = f2b(acc1[r] + bias);
            }
        }
        __syncthreads();

        if (wave < 4) {
            const int mt = wave & 1, nt = wave >> 1;
            f32x4 acc = {0.f, 0.f, 0.f, 0.f};
            const short* ap = &qs[mt * 16 + lr][lg * 8];
            const short* bp = &xs[nt * 16 + lr][lg * 8];
            #pragma unroll
            for (int k = 0; k < 10; ++k) {
                bf16x8 a = *reinterpret_cast<const bf16x8*>(ap + k * 32);
                bf16x8 b = *reinterpret_cast<const bf16x8*>(bp + k * 32);
                acc = __builtin_amdgcn_mfma_f32_16x16x32_bf16(a, b, acc, 0, 0, 0);
            }
            #pragma unroll
            for (int r = 0; r < 4; ++r)
                sc[mt * 16 + lg * 4 + r][nt * 16 + lr] = acc[r] * 0.057735026918962584f;
        }
        __syncthreads();

        if (tid < LL) {
            float mx = -1e30f;
            #pragma unroll
            for (int m = 0; m < LL; ++m) mx = fmaxf(mx, sc[tid][m]);
            float ev[LL], sum = 0.f;
            #pragma unroll
            for (int m = 0; m < LL; ++m) { ev[m] = __expf(sc[tid][m] - mx); sum += ev[m]; }
            const float inv = 1.f / sum;
            #pragma unroll
            for (int m = 0; m < LL; ++m) at[tid][m] = f2b(ev[m] * inv);
            #pragma unroll
            for (int m = LL; m < 32; ++m) at[tid][m] = 0;
        } else if (tid < 32) {
            int* zr = (int*)&at[tid][0];
            #pragma unroll
            for (int m = 0; m < 16; ++m) zr[m] = 0;
        }
        __syncthreads();

        for (int p = wave; p < 19; p += 8) {
            bf16x8 b  = *reinterpret_cast<const bf16x8*>(&xT[p * 16 + lr][lg * 8]);
            bf16x8 a0 = *reinterpret_cast<const bf16x8*>(&at[lr][lg * 8]);
            bf16x8 a1 = *reinterpret_cast<const bf16x8*>(&at[16 + lr][lg * 8]);
            f32x4 z = {0.f, 0.f, 0.f, 0.f};
            f32x4 c0 = __builtin_amdgcn_mfma_f32_16x16x32_bf16(a0, b, z, 0, 0, 0);
            f32x4 c1 = __builtin_amdgcn_mfma_f32_16x16x32_bf16(a1, b, z, 0, 0, 0);
            const int col = p * 16 + lr;
            #pragma unroll
            for (int r = 0; r < 4; ++r) {
                qs[lg * 4 + r][col]      = f2b(c0[r]);
                qs[16 + lg * 4 + r][col] = f2b(c1[r]);
            }
        }
        __syncthreads();

        if (wave < 2) {
            const int mt = wave;
            f32x4 acc = {0.f, 0.f, 0.f, 0.f};
            const short* ap = &qs[mt * 16 + lr][lg * 8];
            const short* bp = wvt + (size_t)n * VD * 320 + lr * 320 + lg * 8;
            #pragma unroll
            for (int k = 0; k < 10; ++k) {
                bf16x8 a = *reinterpret_cast<const bf16x8*>(ap + k * 32);
                bf16x8 b = *reinterpret_cast<const bf16x8*>(bp + k * 32);
                acc = __builtin_amdgcn_mfma_f32_16x16x32_bf16(a, b, acc, 0, 0, 0);
            }
            #pragma unroll
            for (int r = 0; r < 4; ++r) {
                const int row = mt * 16 + lg * 4 + r;
                if (row < LL)
                    out1[((size_t)bs * LL + row) * HID + n * VD + lr] = acc[r] + vB[n * VD + lr];
            }
        }
        __syncthreads();
    }
}

// ===========================================================================

extern "C" void kernel_launch(void* const* d_in, const int* in_sizes, int n_in,
                              void* d_out, int out_size, void* d_ws, size_t ws_size,
                              hipStream_t stream) {
    const int*   news  = (const int*)d_in[0];
    const float* emb   = (const float*)d_in[1];
    const float* qW    = (const float*)d_in[2];
    const float* qB    = (const float*)d_in[3];
    const float* vW    = (const float*)d_in[4];
    const float* vB    = (const float*)d_in[5];
    const float* keyW  = (const float*)d_in[6];
    const float* keyB  = (const float*)d_in[7];
    const float* query = (const float*)d_in[8];

    float* out1 = (float*)d_out;            // news_embedding: 8192000 floats
    float* out2 = out1 + 8192000;           // news_repr: 409600 floats

    const size_t NEED = ((size_t)10240000 + 1638400 + 81920 + 8192000 + 53248) * 2;

    if (ws_size >= NEED) {
        short* Xb  = (short*)d_ws;                  // 32000*320
        short* WqT = Xb + 10240000;                 // 16*320*320
        short* WvT = WqT + 1638400;                 // 256*320
        short* xv  = WvT + 81920;                   // 32000*256
        short* kwb = xv + 8192000;                  // 208*256

        hipLaunchKernelGGL(build_xb, dim3(10000), dim3(256), 0, stream, news, emb, Xb);
        hipLaunchKernelGGL(build_wqt, dim3(10, 10, 16), dim3(32, 32), 0, stream, qW, qB, WqT);
        hipLaunchKernelGGL(build_wvt, dim3(320), dim3(256), 0, stream, vW, vB, WvT);
        hipLaunchKernelGGL(conv_kw, dim3(208), dim3(256), 0, stream, keyW, kwb);
        hipLaunchKernelGGL(gemm_xv, dim3(2, 250), dim3(256), 0, stream, Xb, WvT, xv);
        hipLaunchKernelGGL(qattn, dim3(800, 16), dim3(512), 0, stream, Xb, WqT, xv, out1);
        hipLaunchKernelGGL(nrms_pool_mfma, dim3(NBS), dim3(256), 0, stream,
                           out1, kwb, keyB, query, out2);
    } else {
        short* wqt = (short*)d_ws;
        short* wvt = wqt + (size_t)NH * 304 * 320;
        short* kwb = wvt + (size_t)NH * VD * 320;

        hipLaunchKernelGGL(transpose_qw, dim3(10, 10, 16), dim3(32, 32), 0, stream, qW, wqt);
        hipLaunchKernelGGL(conv_vw, dim3(320), dim3(256), 0, stream, vW, wvt);
        hipLaunchKernelGGL(conv_kw, dim3(208), dim3(256), 0, stream, keyW, kwb);
        hipLaunchKernelGGL(nrms_attn_mfma, dim3(NBS), dim3(512), 0, stream,
                           news, emb, wqt, qB, wvt, vB, out1);
        hipLaunchKernelGGL(nrms_pool_mfma, dim3(NBS), dim3(256), 0, stream,
                           out1, kwb, keyB, query, out2);
    }
}